// Round 5
// baseline (503.519 us; speedup 1.0000x reference)
//
#include <hip/hip_runtime.h>
#include <hip/hip_bf16.h>
#include <math.h>

#define MAXDEG 512

typedef short v8s __attribute__((ext_vector_type(8)));
typedef float v4f __attribute__((ext_vector_type(4)));
typedef float v2f __attribute__((ext_vector_type(2)));

// ---------------- block reduce helpers ----------------
__device__ __forceinline__ float blockReduceSum(float v) {
    __shared__ float sh[8];
    int lane = threadIdx.x & 63, w = threadIdx.x >> 6;
    for (int o = 32; o > 0; o >>= 1) v += __shfl_down(v, o);
    __syncthreads();
    if (lane == 0) sh[w] = v;
    __syncthreads();
    if (w == 0) {
        int nw = (blockDim.x + 63) >> 6;
        v = (lane < nw) ? sh[lane] : 0.f;
        for (int o = 4; o > 0; o >>= 1) v += __shfl_down(v, o);
        if (lane == 0) sh[0] = v;
    }
    __syncthreads();
    return sh[0];
}

__device__ __forceinline__ float blockReduceMax(float v) {
    __shared__ float sh[8];
    int lane = threadIdx.x & 63, w = threadIdx.x >> 6;
    for (int o = 32; o > 0; o >>= 1) v = fmaxf(v, __shfl_down(v, o));
    __syncthreads();
    if (lane == 0) sh[w] = v;
    __syncthreads();
    if (w == 0) {
        int nw = (blockDim.x + 63) >> 6;
        v = (lane < nw) ? sh[lane] : -3.4e38f;
        for (int o = 4; o > 0; o >>= 1) v = fmaxf(v, __shfl_down(v, o));
        if (lane == 0) sh[0] = v;
    }
    __syncthreads();
    return sh[0];
}

// ---------------- kernels ----------------

__global__ void zero_f32(float* __restrict__ p, int n) {
    int i = blockIdx.x * 256 + threadIdx.x;
    if (i < n) p[i] = 0.f;
}

// CSR build + s_mat row sum in one pass.
__global__ void csr_rowsum(const float* __restrict__ adj, const float* __restrict__ s,
                           int* __restrict__ colIdx, int* __restrict__ deg,
                           float* __restrict__ dv, int N) {
    int row = blockIdx.x;
    __shared__ int cnt;
    if (threadIdx.x == 0) cnt = 0;
    __syncthreads();
    const float* ar = adj + (size_t)row * N;
    const float* sr = s + (size_t)row * N;
    int* outp = colIdx + (size_t)row * MAXDEG;
    float psum = 0.f;
    for (int j = threadIdx.x; j < N; j += blockDim.x) {
        psum += sr[j];
        if (ar[j] > 0.f) {
            int p = atomicAdd(&cnt, 1);
            if (p < MAXDEG) outp[p] = j;
        }
    }
    psum = blockReduceSum(psum);
    __syncthreads();
    if (threadIdx.x == 0) {
        deg[row] = cnt < MAXDEG ? cnt : MAXDEG;
        dv[row] = psum;
    }
}

__global__ void hin_kernel(const float* __restrict__ x, const int* __restrict__ obs,
                           const float* __restrict__ theta, __hip_bfloat16* __restrict__ hin,
                           int NF) {
    int i = blockIdx.x * 256 + threadIdx.x;
    if (i >= NF) return;
    int n = i >> 9, f = i & 511;   // F = 512
    float v = x[i];
    if (obs[n] == 1) v += theta[f];
    hin[i] = __float2bfloat16(v);
}

// Wt[b][m][k] = bf16(W[b][k][m])
__global__ void conv_wt(const float* __restrict__ W, __hip_bfloat16* __restrict__ Wt,
                        int K, int M) {
    int b = blockIdx.y;
    size_t i = (size_t)blockIdx.x * 256 + threadIdx.x;
    if (i >= (size_t)M * K) return;
    int mm = (int)(i / K), kk = (int)(i % K);
    Wt[(size_t)b * M * K + i] = __float2bfloat16(W[(size_t)b * K * M + (size_t)kk * M + mm]);
}

// C[b] = A[b] @ Bt[b]^T, C in FP32 (consumed only by the f32 gather),
// with fused el/er epilogue (atomicAdd partials).
__global__ __launch_bounds__(256) void gemm_mfma(
    const __hip_bfloat16* __restrict__ A, const __hip_bfloat16* __restrict__ Bt,
    float* __restrict__ C, int N, int K, int M,
    size_t sA, size_t sB, size_t sC,
    const float* __restrict__ aVec, size_t aStride,
    float* __restrict__ el, float* __restrict__ er) {
    int b = blockIdx.z;
    const unsigned short* Ag = (const unsigned short*)(A + (size_t)b * sA);
    const unsigned short* Bg = (const unsigned short*)(Bt + (size_t)b * sB);
    float* Cg = C + (size_t)b * sC;
    const float* av = aVec + (size_t)b * aStride;

    __shared__ __align__(16) unsigned short As[64][40];
    __shared__ __align__(16) unsigned short Bs[64][40];

    const int tid = threadIdx.x;
    const int wave = tid >> 6, lane = tid & 63;
    const int row0 = blockIdx.y * 64, col0 = blockIdx.x * 64;
    const int sRow = tid >> 2;
    const int sOff = (tid & 3) * 8;
    const int m = lane & 15, quad = lane >> 4;

    v4f acc[4];
    #pragma unroll
    for (int c = 0; c < 4; c++) acc[c] = (v4f)(0.f);

    for (int k0 = 0; k0 < K; k0 += 32) {
        *(int4*)(&As[sRow][sOff]) =
            *(const int4*)(Ag + (size_t)(row0 + sRow) * K + k0 + sOff);
        *(int4*)(&Bs[sRow][sOff]) =
            *(const int4*)(Bg + (size_t)(col0 + sRow) * K + k0 + sOff);
        __syncthreads();
        v8s af = *(const v8s*)(&As[wave * 16 + m][quad * 8]);
        #pragma unroll
        for (int c = 0; c < 4; c++) {
            v8s bf = *(const v8s*)(&Bs[c * 16 + m][quad * 8]);
            acc[c] = __builtin_amdgcn_mfma_f32_16x16x32_bf16(af, bf, acc[c], 0, 0, 0);
        }
        __syncthreads();
    }
    // C store (fp32)
    #pragma unroll
    for (int c = 0; c < 4; c++)
        #pragma unroll
        for (int r = 0; r < 4; r++) {
            int row = row0 + wave * 16 + quad * 4 + r;
            int col = col0 + c * 16 + m;
            Cg[(size_t)row * M + col] = acc[c][r];
        }
    // fused el/er partials
    float ael[4], aer[4];
    #pragma unroll
    for (int c = 0; c < 4; c++) {
        ael[c] = av[col0 + c * 16 + m];
        aer[c] = av[M + col0 + c * 16 + m];
    }
    #pragma unroll
    for (int r = 0; r < 4; r++) {
        float pel = 0.f, per_ = 0.f;
        #pragma unroll
        for (int c = 0; c < 4; c++) {
            pel += acc[c][r] * ael[c];
            per_ += acc[c][r] * aer[c];
        }
        #pragma unroll
        for (int off = 1; off < 16; off <<= 1) {
            pel += __shfl_xor(pel, off);
            per_ += __shfl_xor(per_, off);
        }
        if (m == 0) {
            int row = row0 + wave * 16 + quad * 4 + r;
            atomicAdd(&el[(size_t)b * N + row], pel);
            atomicAdd(&er[(size_t)b * N + row], per_);
        }
    }
}

// Masked softmax + f32 gather. Block = 256 thr (4 waves).
// Lane covers 4 dims (float4 load, no dtype conversion). Neighbor list is
// padded with p=0 entries so the inner loop has no tail predicates.
// HEADS==4: XCD clustering (head h -> blocks with blk%8 in {2h,2h+1}).
template<int D, int ACT, int HEADS>
__global__ __launch_bounds__(256) void attn_vec(
    const float* __restrict__ Wh, const float* __restrict__ el,
    const float* __restrict__ er, const int* __restrict__ colIdx,
    const int* __restrict__ deg, __hip_bfloat16* __restrict__ out,
    int N, size_t sWh, size_t sOut, int outRowStride) {
    constexpr int LPN = D / 4;        // lanes per neighbor
    constexpr int NPW = 64 / LPN;     // neighbors per wave-step
    constexpr int STRIDE = 4 * NPW;   // neighbors per block-step
    constexpr int PAD = 2 * STRIDE;   // unroll-2 consumption granularity

    int b, row;
    if (HEADS == 4) {
        int blk = blockIdx.x;
        b = (blk & 7) >> 1;
        row = ((blk >> 3) << 1) | (blk & 1);
    } else {
        b = 0;
        row = blockIdx.x;
    }
    const int tid = threadIdx.x;
    const float* whb = Wh + (size_t)b * sWh;
    const float* erb = er + (size_t)b * N;
    const float eln = el[(size_t)b * N + row];
    const int dc = deg[row];
    const int dcp = (dc + PAD - 1) & ~(PAD - 1);
    const int* ci = colIdx + (size_t)row * MAXDEG;

    __shared__ __align__(16) float2 spc[MAXDEG];  // {p, asint(j*D)}
    __shared__ __align__(16) float redc[4 * D];

    float mx = -3.4e38f;
    for (int k = tid; k < dc; k += 256) {
        int j = ci[k];
        float s = eln + erb[j];
        s = fmaxf(s, 0.2f * s);               // LeakyReLU(0.2)
        spc[k] = make_float2(s, __int_as_float(j * D));
        mx = fmaxf(mx, s);
    }
    // pad with zero-weight entries pointing at row 0 (valid memory)
    for (int k = dc + tid; k < dcp; k += 256)
        spc[k] = make_float2(0.f, __int_as_float(0));
    mx = blockReduceMax(mx);
    float l = 0.f;
    for (int k = tid; k < dc; k += 256) {
        float p = __expf(spc[k].x - mx);
        spc[k].x = p;
        l += p;
    }
    l = blockReduceSum(l);
    const float inv = 1.f / l;

    const int wave = tid >> 6, lane = tid & 63;
    const int sub = lane / LPN;
    const int dl = (lane % LPN) * 4;
    const float* wp = whb + dl;

    v2f a0[2], a1[2];
    a0[0] = (v2f)(0.f); a0[1] = (v2f)(0.f);
    a1[0] = (v2f)(0.f); a1[1] = (v2f)(0.f);

    for (int k = wave * NPW + sub; k < dcp; k += 2 * STRIDE) {
        float2 pc0 = spc[k];
        float2 pc1 = spc[k + STRIDE];
        const float4 r0 = *(const float4*)(wp + __float_as_int(pc0.y));
        const float4 r1 = *(const float4*)(wp + __float_as_int(pc1.y));
        v2f p0 = (v2f){pc0.x, pc0.x}, p1 = (v2f){pc1.x, pc1.x};
        a0[0] += p0 * (v2f){r0.x, r0.y};
        a0[1] += p0 * (v2f){r0.z, r0.w};
        a1[0] += p1 * (v2f){r1.x, r1.y};
        a1[1] += p1 * (v2f){r1.z, r1.w};
    }
    a0[0] += a1[0];
    a0[1] += a1[1];
    // reduce across sub-groups (no-op when LPN==64)
    #pragma unroll
    for (int off = LPN; off < 64; off <<= 1) {
        a0[0][0] += __shfl_xor(a0[0][0], off);
        a0[0][1] += __shfl_xor(a0[0][1], off);
        a0[1][0] += __shfl_xor(a0[1][0], off);
        a0[1][1] += __shfl_xor(a0[1][1], off);
    }
    __syncthreads();
    if (sub == 0)
        *(float4*)(&redc[wave * D + dl]) =
            make_float4(a0[0][0], a0[0][1], a0[1][0], a0[1][1]);
    __syncthreads();
    if (tid < D) {
        float v = (redc[tid] + redc[D + tid] + redc[2 * D + tid] + redc[3 * D + tid]) * inv;
        if (ACT == 1) v = (v > 0.f) ? v : expm1f(v);   // ELU
        out[(size_t)b * sOut + (size_t)row * outRowStride + tid] = __float2bfloat16(v);
    }
}

// D==1 attention (output layer 2)
__global__ void attn_d1(const __hip_bfloat16* __restrict__ Wh, const float* __restrict__ el,
                        const float* __restrict__ er, const int* __restrict__ colIdx,
                        const int* __restrict__ deg, __hip_bfloat16* __restrict__ out, int N) {
    int row = blockIdx.x, tid = threadIdx.x;
    const float eln = el[row];
    const int dc = deg[row];
    const int* ci = colIdx + (size_t)row * MAXDEG;
    __shared__ float sp[MAXDEG];
    __shared__ int sc[MAXDEG];
    float mx = -3.4e38f;
    for (int k = tid; k < dc; k += blockDim.x) {
        int j = ci[k];
        sc[k] = j;
        float s = eln + er[j];
        s = fmaxf(s, 0.2f * s);
        sp[k] = s;
        mx = fmaxf(mx, s);
    }
    mx = blockReduceMax(mx);
    float l = 0.f, acc = 0.f;
    for (int k = tid; k < dc; k += blockDim.x) {
        float p = __expf(sp[k] - mx);
        l += p;
        acc += p * __bfloat162float(Wh[sc[k]]);
    }
    l = blockReduceSum(l);
    acc = blockReduceSum(acc);
    if (tid == 0) out[row] = __float2bfloat16(acc / l);
}

// o2Wh[n] = o1o[n,:64]·Wo1[:,0]; fused el4/er4 = o2Wh*ao1[0/1]
__global__ void matvec64_kernel(const __hip_bfloat16* __restrict__ h3,
                                const float* __restrict__ w,
                                const float* __restrict__ ao1,
                                __hip_bfloat16* __restrict__ out,
                                float* __restrict__ el4, float* __restrict__ er4, int N) {
    int row = blockIdx.x;
    float v = __bfloat162float(h3[(size_t)row * 64 + threadIdx.x]) * w[threadIdx.x];
    for (int o = 32; o > 0; o >>= 1) v += __shfl_down(v, o);
    if (threadIdx.x == 0) {
        out[row] = __float2bfloat16(v);
        el4[row] = v * ao1[0];
        er4[row] = v * ao1[1];
    }
}

__device__ __forceinline__ float leaky(float x) { return x >= 0.f ? x : 0.2f * x; }

__global__ void degree_nn(const __hip_bfloat16* __restrict__ h4, const float* __restrict__ dv,
                          const float* __restrict__ dW, const float* __restrict__ dW0,
                          const float* __restrict__ dW1, const float* __restrict__ dW01,
                          const float* __restrict__ dW2, const float* __restrict__ dW02,
                          const float* __restrict__ dV, const float* __restrict__ dV0,
                          float* __restrict__ out, int N) {
    int n = blockIdx.x * blockDim.x + threadIdx.x;
    if (n >= N) return;
    float h = __bfloat162float(h4[n]);
    h = (h > 0.f) ? h : expm1f(h);            // elu
    float d = dv[n];
    float t0[10], t1[20], t2[10];
    #pragma unroll
    for (int i = 0; i < 10; i++)
        t0[i] = leaky(h * dW[i] + d * dW[10 + i] + dW0[i]);
    #pragma unroll
    for (int j = 0; j < 20; j++) {
        float s = dW01[j];
        #pragma unroll
        for (int i = 0; i < 10; i++) s += t0[i] * dW1[i * 20 + j];
        t1[j] = leaky(s);
    }
    #pragma unroll
    for (int j = 0; j < 10; j++) {
        float s = dW02[j];
        #pragma unroll
        for (int i = 0; i < 20; i++) s += t1[i] * dW2[i * 10 + j];
        t2[j] = leaky(s);
    }
    float o = dV0[0];
    #pragma unroll
    for (int i = 0; i < 10; i++) o += t2[i] * dV[i];
    out[n] = leaky(o);
}

// ---------------- launch ----------------
extern "C" void kernel_launch(void* const* d_in, const int* in_sizes, int n_in,
                              void* d_out, int out_size, void* d_ws, size_t ws_size,
                              hipStream_t stream) {
    const int N = 4096, F = 512, H = 4, D1 = 256, O1 = 64;
    const float* x     = (const float*)d_in[0];
    const float* adj   = (const float*)d_in[1];
    const int*   obs   = (const int*)  d_in[2];
    const float* s_mat = (const float*)d_in[3];
    const float* theta = (const float*)d_in[4];
    const float* Wh0   = (const float*)d_in[5];
    const float* ah0   = (const float*)d_in[6];
    const float* Wh1   = (const float*)d_in[7];
    const float* ah1   = (const float*)d_in[8];
    const float* Wo0   = (const float*)d_in[9];
    const float* ao0   = (const float*)d_in[10];
    const float* Wo1   = (const float*)d_in[11];
    const float* ao1   = (const float*)d_in[12];
    const float* dWp   = (const float*)d_in[13];
    const float* dW0p  = (const float*)d_in[14];
    const float* dW1p  = (const float*)d_in[15];
    const float* dW01p = (const float*)d_in[16];
    const float* dW2p  = (const float*)d_in[17];
    const float* dW02p = (const float*)d_in[18];
    const float* dVp   = (const float*)d_in[19];
    const float* dV0p  = (const float*)d_in[20];
    float* outp = (float*)d_out;

    char* ws = (char*)d_ws;
    auto alloc = [&](size_t bytes) {
        char* p = ws;
        ws += (bytes + 255) & ~(size_t)255;
        return p;
    };
    typedef __hip_bfloat16 bf;
    bf* hin     = (bf*)alloc((size_t)N * F * 2);
    float* whA  = (float*)alloc((size_t)H * N * D1 * 4);   // GEMM out, fp32
    bf* hb      = (bf*)alloc((size_t)H * N * D1 * 2);
    bf* hcat    = (bf*)alloc((size_t)N * H * D1 * 2);
    float* o1Wh = (float*)alloc((size_t)N * O1 * 4);
    bf* o1o     = (bf*)alloc((size_t)N * O1 * 2);
    bf* o2Wh    = (bf*)alloc((size_t)N * 2);
    bf* o2o     = (bf*)alloc((size_t)N * 2);
    bf* Wh0t    = (bf*)alloc((size_t)H * F * D1 * 2);
    bf* Wh1t    = (bf*)alloc((size_t)H * D1 * D1 * 2);
    bf* Wo0t    = (bf*)alloc((size_t)H * D1 * O1 * 2);
    int elerN = 4 * H * N + 2 * N;
    float* elerZ = (float*)alloc((size_t)elerN * 4);
    float* el1 = elerZ;
    float* er1 = el1 + H * N;
    float* el2 = er1 + H * N;
    float* er2 = el2 + H * N;
    float* el3 = er2 + H * N;
    float* er3 = el3 + N;
    float* el4 = (float*)alloc((size_t)N * 4);
    float* er4 = (float*)alloc((size_t)N * 4);
    float* dv  = (float*)alloc((size_t)N * 4);
    int* colIdx = (int*)alloc((size_t)N * MAXDEG * 4);
    int* deg    = (int*)alloc((size_t)N * 4);

    zero_f32<<<(elerN + 255) / 256, 256, 0, stream>>>(elerZ, elerN);
    csr_rowsum<<<N, 256, 0, stream>>>(adj, s_mat, colIdx, deg, dv, N);
    hin_kernel<<<(N * F + 255) / 256, 256, 0, stream>>>(x, obs, theta, hin, N * F);
    conv_wt<<<dim3((F * D1 + 255) / 256, H), 256, 0, stream>>>(Wh0, Wh0t, F, D1);
    conv_wt<<<dim3((D1 * D1 + 255) / 256, H), 256, 0, stream>>>(Wh1, Wh1t, D1, D1);
    conv_wt<<<dim3((H * D1 * O1 + 255) / 256, 1), 256, 0, stream>>>(Wo0, Wo0t, H * D1, O1);

    // ----- multi-head layer 1 (D=256, elu) -----
    gemm_mfma<<<dim3(D1 / 64, N / 64, H), 256, 0, stream>>>(
        hin, Wh0t, whA, N, F, D1, 0, (size_t)D1 * F, (size_t)N * D1,
        ah0, (size_t)2 * D1, el1, er1);
    attn_vec<256, 1, 4><<<N * H, 256, 0, stream>>>(
        whA, el1, er1, colIdx, deg, hb,
        N, (size_t)N * D1, (size_t)N * D1, D1);

    // ----- multi-head layer 2 (D=256, elu) -> hcat interleaved -----
    gemm_mfma<<<dim3(D1 / 64, N / 64, H), 256, 0, stream>>>(
        hb, Wh1t, whA, N, D1, D1, (size_t)N * D1, (size_t)D1 * D1, (size_t)N * D1,
        ah1, (size_t)2 * D1, el2, er2);
    attn_vec<256, 1, 4><<<N * H, 256, 0, stream>>>(
        whA, el2, er2, colIdx, deg, hcat,
        N, (size_t)N * D1, (size_t)D1, H * D1);

    // ----- output layer 1 (D=64, no act) -----
    gemm_mfma<<<dim3(O1 / 64, N / 64, 1), 256, 0, stream>>>(
        hcat, Wo0t, o1Wh, N, H * D1, O1, 0, 0, 0,
        ao0, 0, el3, er3);
    attn_vec<64, 0, 1><<<N, 256, 0, stream>>>(
        o1Wh, el3, er3, colIdx, deg, o1o, N, 0, 0, O1);

    // ----- output layer 2 (D=1, no act) -----
    matvec64_kernel<<<N, 64, 0, stream>>>(o1o, Wo1, ao1, o2Wh, el4, er4, N);
    attn_d1<<<N, 256, 0, stream>>>(o2Wh, el4, er4, colIdx, deg, o2o, N);

    // ----- elu + degreeNN -----
    degree_nn<<<(N + 255) / 256, 256, 0, stream>>>(o2o, dv, dWp, dW0p, dW1p,
        dW01p, dW2p, dW02p, dVp, dV0p, outp, N);
}

// Round 6
// 427.821 us; speedup vs baseline: 1.1769x; 1.1769x over previous
//
#include <hip/hip_runtime.h>
#include <hip/hip_bf16.h>
#include <math.h>

#define MAXDEG 512

typedef short v8s __attribute__((ext_vector_type(8)));
typedef float v4f __attribute__((ext_vector_type(4)));
typedef float v2f __attribute__((ext_vector_type(2)));
typedef __hip_bfloat16 bf;

// ---------------- block reduce helpers ----------------
__device__ __forceinline__ float blockReduceSum(float v) {
    __shared__ float sh[8];
    int lane = threadIdx.x & 63, w = threadIdx.x >> 6;
    for (int o = 32; o > 0; o >>= 1) v += __shfl_down(v, o);
    __syncthreads();
    if (lane == 0) sh[w] = v;
    __syncthreads();
    if (w == 0) {
        int nw = (blockDim.x + 63) >> 6;
        v = (lane < nw) ? sh[lane] : 0.f;
        for (int o = 4; o > 0; o >>= 1) v += __shfl_down(v, o);
        if (lane == 0) sh[0] = v;
    }
    __syncthreads();
    return sh[0];
}

__device__ __forceinline__ float blockReduceMax(float v) {
    __shared__ float sh[8];
    int lane = threadIdx.x & 63, w = threadIdx.x >> 6;
    for (int o = 32; o > 0; o >>= 1) v = fmaxf(v, __shfl_down(v, o));
    __syncthreads();
    if (lane == 0) sh[w] = v;
    __syncthreads();
    if (w == 0) {
        int nw = (blockDim.x + 63) >> 6;
        v = (lane < nw) ? sh[lane] : -3.4e38f;
        for (int o = 4; o > 0; o >>= 1) v = fmaxf(v, __shfl_down(v, o));
        if (lane == 0) sh[0] = v;
    }
    __syncthreads();
    return sh[0];
}

__device__ __forceinline__ v2f bf2f(unsigned int u) {
    union { unsigned int u; float f; } lo, hi;
    lo.u = u << 16;
    hi.u = u & 0xffff0000u;
    return (v2f){lo.f, hi.f};
}

__device__ __forceinline__ void acc_add(v2f* a, float p, const uint4& r) {
    v2f pp = (v2f){p, p};
    a[0] += pp * bf2f(r.x);
    a[1] += pp * bf2f(r.y);
    a[2] += pp * bf2f(r.z);
    a[3] += pp * bf2f(r.w);
}

// ---------------- kernels ----------------

__global__ void zero_f32(float* __restrict__ p, int n) {
    int i = blockIdx.x * 256 + threadIdx.x;
    if (i < n) p[i] = 0.f;
}

// CSR build + s_mat row sum in one pass.
__global__ void csr_rowsum(const float* __restrict__ adj, const float* __restrict__ s,
                           int* __restrict__ colIdx, int* __restrict__ deg,
                           float* __restrict__ dv, int N) {
    int row = blockIdx.x;
    __shared__ int cnt;
    if (threadIdx.x == 0) cnt = 0;
    __syncthreads();
    const float* ar = adj + (size_t)row * N;
    const float* sr = s + (size_t)row * N;
    int* outp = colIdx + (size_t)row * MAXDEG;
    float psum = 0.f;
    for (int j = threadIdx.x; j < N; j += blockDim.x) {
        psum += sr[j];
        if (ar[j] > 0.f) {
            int p = atomicAdd(&cnt, 1);
            if (p < MAXDEG) outp[p] = j;
        }
    }
    psum = blockReduceSum(psum);
    __syncthreads();
    if (threadIdx.x == 0) {
        deg[row] = cnt < MAXDEG ? cnt : MAXDEG;
        dv[row] = psum;
    }
}

// hin (x + seed*theta -> bf16) + three weight transposes, one launch.
__global__ void prep(const float* __restrict__ x, const int* __restrict__ obs,
                     const float* __restrict__ theta,
                     const float* __restrict__ Wh0, const float* __restrict__ Wh1,
                     const float* __restrict__ Wo0,
                     bf* __restrict__ hin, bf* __restrict__ Wh0t,
                     bf* __restrict__ Wh1t, bf* __restrict__ Wo0t) {
    const int n0 = 4096 * 512;       // hin
    const int n1 = 4 * 512 * 256;    // Wh0t
    const int n2 = 4 * 256 * 256;    // Wh1t
    const int n3 = 1024 * 64;        // Wo0t
    int i = blockIdx.x * 256 + threadIdx.x;
    if (i < n0) {
        int n = i >> 9, f = i & 511;
        float v = x[i];
        if (obs[n] == 1) v += theta[f];
        hin[i] = __float2bfloat16(v);
    } else if (i < n0 + n1) {
        int t = i - n0;                         // [b][m<256][k<512]
        int b = t / (512 * 256), r = t % (512 * 256);
        int mm = r >> 9, kk = r & 511;
        Wh0t[t] = __float2bfloat16(Wh0[b * 512 * 256 + kk * 256 + mm]);
    } else if (i < n0 + n1 + n2) {
        int t = i - n0 - n1;                    // [b][m<256][k<256]
        int b = t >> 16, r = t & 65535;
        int mm = r >> 8, kk = r & 255;
        Wh1t[t] = __float2bfloat16(Wh1[b * 65536 + kk * 256 + mm]);
    } else if (i < n0 + n1 + n2 + n3) {
        int t = i - n0 - n1 - n2;               // [m<64][k<1024]
        int mm = t >> 10, kk = t & 1023;
        Wo0t[t] = __float2bfloat16(Wo0[kk * 64 + mm]);
    }
}

// 128x128 block-tile MFMA GEMM: C[b] = A[b] @ Bt[b]^T (bf16 out) with fused
// el/er epilogue. 4 waves, each computes 64x64 (4x4 grid of 16x16 tiles):
// 16 MFMA per 8 ds_read_b128 per K-chunk. N%128==0, M%128==0, K%32==0.
__global__ __launch_bounds__(256) void gemm_mfma128(
    const bf* __restrict__ A, const bf* __restrict__ Bt,
    bf* __restrict__ C, int N, int K, int M,
    size_t sA, size_t sB, size_t sC,
    const float* __restrict__ aVec, size_t aStride,
    float* __restrict__ el, float* __restrict__ er) {
    int b = blockIdx.z;
    const unsigned short* Ag = (const unsigned short*)(A + (size_t)b * sA);
    const unsigned short* Bg = (const unsigned short*)(Bt + (size_t)b * sB);
    bf* Cg = C + (size_t)b * sC;
    const float* av = aVec + (size_t)b * aStride;

    __shared__ __align__(16) unsigned short As[128][40];
    __shared__ __align__(16) unsigned short Bs[128][40];

    const int tid = threadIdx.x;
    const int wave = tid >> 6, lane = tid & 63;
    const int wm = wave >> 1, wn = wave & 1;
    const int row0 = blockIdx.y * 128, col0 = blockIdx.x * 128;
    const int lr = tid >> 2;            // 0..63
    const int lo = (tid & 3) * 8;       // 0,8,16,24
    const int m = lane & 15, quad = lane >> 4;

    v4f acc[4][4];
    #pragma unroll
    for (int i = 0; i < 4; i++)
        #pragma unroll
        for (int c = 0; c < 4; c++) acc[i][c] = (v4f)(0.f);

    for (int k0 = 0; k0 < K; k0 += 32) {
        *(int4*)(&As[lr][lo]) =
            *(const int4*)(Ag + (size_t)(row0 + lr) * K + k0 + lo);
        *(int4*)(&As[lr + 64][lo]) =
            *(const int4*)(Ag + (size_t)(row0 + 64 + lr) * K + k0 + lo);
        *(int4*)(&Bs[lr][lo]) =
            *(const int4*)(Bg + (size_t)(col0 + lr) * K + k0 + lo);
        *(int4*)(&Bs[lr + 64][lo]) =
            *(const int4*)(Bg + (size_t)(col0 + 64 + lr) * K + k0 + lo);
        __syncthreads();
        v8s af[4], bfv[4];
        #pragma unroll
        for (int i = 0; i < 4; i++)
            af[i] = *(const v8s*)(&As[wm * 64 + i * 16 + m][quad * 8]);
        #pragma unroll
        for (int c = 0; c < 4; c++)
            bfv[c] = *(const v8s*)(&Bs[wn * 64 + c * 16 + m][quad * 8]);
        #pragma unroll
        for (int i = 0; i < 4; i++)
            #pragma unroll
            for (int c = 0; c < 4; c++)
                acc[i][c] = __builtin_amdgcn_mfma_f32_16x16x32_bf16(
                    af[i], bfv[c], acc[i][c], 0, 0, 0);
        __syncthreads();
    }
    // C store (bf16)
    #pragma unroll
    for (int i = 0; i < 4; i++)
        #pragma unroll
        for (int c = 0; c < 4; c++)
            #pragma unroll
            for (int r = 0; r < 4; r++) {
                int row = row0 + wm * 64 + i * 16 + quad * 4 + r;
                int col = col0 + wn * 64 + c * 16 + m;
                Cg[(size_t)row * M + col] = __float2bfloat16(acc[i][c][r]);
            }
    // fused el/er partials
    float ael[4], aer[4];
    #pragma unroll
    for (int c = 0; c < 4; c++) {
        ael[c] = av[col0 + wn * 64 + c * 16 + m];
        aer[c] = av[M + col0 + wn * 64 + c * 16 + m];
    }
    #pragma unroll
    for (int i = 0; i < 4; i++)
        #pragma unroll
        for (int r = 0; r < 4; r++) {
            float pel = 0.f, per_ = 0.f;
            #pragma unroll
            for (int c = 0; c < 4; c++) {
                pel += acc[i][c][r] * ael[c];
                per_ += acc[i][c][r] * aer[c];
            }
            #pragma unroll
            for (int off = 1; off < 16; off <<= 1) {
                pel += __shfl_xor(pel, off);
                per_ += __shfl_xor(per_, off);
            }
            if (m == 0) {
                int row = row0 + wm * 64 + i * 16 + quad * 4 + r;
                atomicAdd(&el[(size_t)b * N + row], pel);
                atomicAdd(&er[(size_t)b * N + row], per_);
            }
        }
}

// 64x64 tile GEMM (for M=64 output layer), bf16 out, fused el/er.
__global__ __launch_bounds__(256) void gemm_mfma64(
    const bf* __restrict__ A, const bf* __restrict__ Bt,
    bf* __restrict__ C, int N, int K, int M,
    size_t sA, size_t sB, size_t sC,
    const float* __restrict__ aVec, size_t aStride,
    float* __restrict__ el, float* __restrict__ er) {
    int b = blockIdx.z;
    const unsigned short* Ag = (const unsigned short*)(A + (size_t)b * sA);
    const unsigned short* Bg = (const unsigned short*)(Bt + (size_t)b * sB);
    bf* Cg = C + (size_t)b * sC;
    const float* av = aVec + (size_t)b * aStride;

    __shared__ __align__(16) unsigned short As[64][40];
    __shared__ __align__(16) unsigned short Bs[64][40];

    const int tid = threadIdx.x;
    const int wave = tid >> 6, lane = tid & 63;
    const int row0 = blockIdx.y * 64, col0 = blockIdx.x * 64;
    const int sRow = tid >> 2;
    const int sOff = (tid & 3) * 8;
    const int m = lane & 15, quad = lane >> 4;

    v4f acc[4];
    #pragma unroll
    for (int c = 0; c < 4; c++) acc[c] = (v4f)(0.f);

    for (int k0 = 0; k0 < K; k0 += 32) {
        *(int4*)(&As[sRow][sOff]) =
            *(const int4*)(Ag + (size_t)(row0 + sRow) * K + k0 + sOff);
        *(int4*)(&Bs[sRow][sOff]) =
            *(const int4*)(Bg + (size_t)(col0 + sRow) * K + k0 + sOff);
        __syncthreads();
        v8s af = *(const v8s*)(&As[wave * 16 + m][quad * 8]);
        #pragma unroll
        for (int c = 0; c < 4; c++) {
            v8s bfv = *(const v8s*)(&Bs[c * 16 + m][quad * 8]);
            acc[c] = __builtin_amdgcn_mfma_f32_16x16x32_bf16(af, bfv, acc[c], 0, 0, 0);
        }
        __syncthreads();
    }
    #pragma unroll
    for (int c = 0; c < 4; c++)
        #pragma unroll
        for (int r = 0; r < 4; r++) {
            int row = row0 + wave * 16 + quad * 4 + r;
            int col = col0 + c * 16 + m;
            Cg[(size_t)row * M + col] = __float2bfloat16(acc[c][r]);
        }
    float ael[4], aer[4];
    #pragma unroll
    for (int c = 0; c < 4; c++) {
        ael[c] = av[col0 + c * 16 + m];
        aer[c] = av[M + col0 + c * 16 + m];
    }
    #pragma unroll
    for (int r = 0; r < 4; r++) {
        float pel = 0.f, per_ = 0.f;
        #pragma unroll
        for (int c = 0; c < 4; c++) {
            pel += acc[c][r] * ael[c];
            per_ += acc[c][r] * aer[c];
        }
        #pragma unroll
        for (int off = 1; off < 16; off <<= 1) {
            pel += __shfl_xor(pel, off);
            per_ += __shfl_xor(per_, off);
        }
        if (m == 0) {
            int row = row0 + wave * 16 + quad * 4 + r;
            atomicAdd(&el[(size_t)b * N + row], pel);
            atomicAdd(&er[(size_t)b * N + row], per_);
        }
    }
}

// Masked softmax + bf16 gather (L2-resident footprint). Lane covers 8 dims
// (uint4 load). Offsets j*D precomputed; list padded with p=0 entries.
// HEADS==4: XCD clustering (head h -> blocks with blk%8 in {2h,2h+1}).
template<int D, int ACT, int HEADS>
__global__ __launch_bounds__(256) void attn_vec(
    const unsigned short* __restrict__ Wh, const float* __restrict__ el,
    const float* __restrict__ er, const int* __restrict__ colIdx,
    const int* __restrict__ deg, bf* __restrict__ out,
    int N, size_t sWh, size_t sOut, int outRowStride) {
    constexpr int LPN = D / 8;        // lanes per neighbor
    constexpr int NPW = 64 / LPN;     // neighbors per wave-step
    constexpr int STRIDE = 4 * NPW;   // neighbors per block-step
    constexpr int PAD = 2 * STRIDE;   // unroll-2 granularity

    int b, row;
    if (HEADS == 4) {
        int blk = blockIdx.x;
        b = (blk & 7) >> 1;
        row = ((blk >> 3) << 1) | (blk & 1);
    } else {
        b = 0;
        row = blockIdx.x;
    }
    const int tid = threadIdx.x;
    const unsigned short* whb = Wh + (size_t)b * sWh;
    const float* erb = er + (size_t)b * N;
    const float eln = el[(size_t)b * N + row];
    const int dc = deg[row];
    const int dcp = (dc + PAD - 1) & ~(PAD - 1);
    const int* ci = colIdx + (size_t)row * MAXDEG;

    __shared__ __align__(16) float2 spc[MAXDEG];  // {p, asint(j*D)}
    __shared__ __align__(16) float redc[4 * D];

    float mx = -3.4e38f;
    for (int k = tid; k < dc; k += 256) {
        int j = ci[k];
        float s = eln + erb[j];
        s = fmaxf(s, 0.2f * s);               // LeakyReLU(0.2)
        spc[k] = make_float2(s, __int_as_float(j * D));
        mx = fmaxf(mx, s);
    }
    for (int k = dc + tid; k < dcp; k += 256)
        spc[k] = make_float2(0.f, __int_as_float(0));
    mx = blockReduceMax(mx);
    float l = 0.f;
    for (int k = tid; k < dc; k += 256) {
        float p = __expf(spc[k].x - mx);
        spc[k].x = p;
        l += p;
    }
    l = blockReduceSum(l);
    const float inv = 1.f / l;

    const int wave = tid >> 6, lane = tid & 63;
    const int sub = lane / LPN;
    const int dl = (lane % LPN) * 8;
    const unsigned short* wp = whb + dl;

    v2f a0[4], a1[4];
    #pragma unroll
    for (int i = 0; i < 4; i++) { a0[i] = (v2f)(0.f); a1[i] = (v2f)(0.f); }

    for (int k = wave * NPW + sub; k < dcp; k += 2 * STRIDE) {
        float2 pc0 = spc[k];
        float2 pc1 = spc[k + STRIDE];
        const uint4 r0 = *(const uint4*)(wp + __float_as_int(pc0.y));
        const uint4 r1 = *(const uint4*)(wp + __float_as_int(pc1.y));
        acc_add(a0, pc0.x, r0);
        acc_add(a1, pc1.x, r1);
    }
    #pragma unroll
    for (int i = 0; i < 4; i++) a0[i] += a1[i];
    // reduce across sub-groups
    #pragma unroll
    for (int off = LPN; off < 64; off <<= 1)
        #pragma unroll
        for (int i = 0; i < 4; i++) {
            a0[i][0] += __shfl_xor(a0[i][0], off);
            a0[i][1] += __shfl_xor(a0[i][1], off);
        }
    __syncthreads();
    if (sub == 0)
        #pragma unroll
        for (int i = 0; i < 4; i++)
            *(float2*)(&redc[wave * D + dl + 2 * i]) = make_float2(a0[i][0], a0[i][1]);
    __syncthreads();
    if (tid < D) {
        float v = (redc[tid] + redc[D + tid] + redc[2 * D + tid] + redc[3 * D + tid]) * inv;
        if (ACT == 1) v = (v > 0.f) ? v : expm1f(v);   // ELU
        out[(size_t)b * sOut + (size_t)row * outRowStride + tid] = __float2bfloat16(v);
    }
}

// D==1 attention (output layer 2)
__global__ void attn_d1(const bf* __restrict__ Wh, const float* __restrict__ el,
                        const float* __restrict__ er, const int* __restrict__ colIdx,
                        const int* __restrict__ deg, bf* __restrict__ out, int N) {
    int row = blockIdx.x, tid = threadIdx.x;
    const float eln = el[row];
    const int dc = deg[row];
    const int* ci = colIdx + (size_t)row * MAXDEG;
    __shared__ float sp[MAXDEG];
    __shared__ int sc[MAXDEG];
    float mx = -3.4e38f;
    for (int k = tid; k < dc; k += blockDim.x) {
        int j = ci[k];
        sc[k] = j;
        float s = eln + er[j];
        s = fmaxf(s, 0.2f * s);
        sp[k] = s;
        mx = fmaxf(mx, s);
    }
    mx = blockReduceMax(mx);
    float l = 0.f, acc = 0.f;
    for (int k = tid; k < dc; k += blockDim.x) {
        float p = __expf(sp[k] - mx);
        l += p;
        acc += p * __bfloat162float(Wh[sc[k]]);
    }
    l = blockReduceSum(l);
    acc = blockReduceSum(acc);
    if (tid == 0) out[row] = __float2bfloat16(acc / l);
}

// o2Wh[n] = o1o[n,:64]·Wo1[:,0]; fused el4/er4 = o2Wh*ao1[0/1]
__global__ void matvec64_kernel(const bf* __restrict__ h3,
                                const float* __restrict__ w,
                                const float* __restrict__ ao1,
                                bf* __restrict__ out,
                                float* __restrict__ el4, float* __restrict__ er4, int N) {
    int row = blockIdx.x;
    float v = __bfloat162float(h3[(size_t)row * 64 + threadIdx.x]) * w[threadIdx.x];
    for (int o = 32; o > 0; o >>= 1) v += __shfl_down(v, o);
    if (threadIdx.x == 0) {
        out[row] = __float2bfloat16(v);
        el4[row] = v * ao1[0];
        er4[row] = v * ao1[1];
    }
}

__device__ __forceinline__ float leaky(float x) { return x >= 0.f ? x : 0.2f * x; }

__global__ void degree_nn(const bf* __restrict__ h4, const float* __restrict__ dv,
                          const float* __restrict__ dW, const float* __restrict__ dW0,
                          const float* __restrict__ dW1, const float* __restrict__ dW01,
                          const float* __restrict__ dW2, const float* __restrict__ dW02,
                          const float* __restrict__ dV, const float* __restrict__ dV0,
                          float* __restrict__ out, int N) {
    int n = blockIdx.x * blockDim.x + threadIdx.x;
    if (n >= N) return;
    float h = __bfloat162float(h4[n]);
    h = (h > 0.f) ? h : expm1f(h);            // elu
    float d = dv[n];
    float t0[10], t1[20], t2[10];
    #pragma unroll
    for (int i = 0; i < 10; i++)
        t0[i] = leaky(h * dW[i] + d * dW[10 + i] + dW0[i]);
    #pragma unroll
    for (int j = 0; j < 20; j++) {
        float s = dW01[j];
        #pragma unroll
        for (int i = 0; i < 10; i++) s += t0[i] * dW1[i * 20 + j];
        t1[j] = leaky(s);
    }
    #pragma unroll
    for (int j = 0; j < 10; j++) {
        float s = dW02[j];
        #pragma unroll
        for (int i = 0; i < 20; i++) s += t1[i] * dW2[i * 10 + j];
        t2[j] = leaky(s);
    }
    float o = dV0[0];
    #pragma unroll
    for (int i = 0; i < 10; i++) o += t2[i] * dV[i];
    out[n] = leaky(o);
}

// ---------------- launch ----------------
extern "C" void kernel_launch(void* const* d_in, const int* in_sizes, int n_in,
                              void* d_out, int out_size, void* d_ws, size_t ws_size,
                              hipStream_t stream) {
    const int N = 4096, F = 512, H = 4, D1 = 256, O1 = 64;
    const float* x     = (const float*)d_in[0];
    const float* adj   = (const float*)d_in[1];
    const int*   obs   = (const int*)  d_in[2];
    const float* s_mat = (const float*)d_in[3];
    const float* theta = (const float*)d_in[4];
    const float* Wh0   = (const float*)d_in[5];
    const float* ah0   = (const float*)d_in[6];
    const float* Wh1   = (const float*)d_in[7];
    const float* ah1   = (const float*)d_in[8];
    const float* Wo0   = (const float*)d_in[9];
    const float* ao0   = (const float*)d_in[10];
    const float* Wo1   = (const float*)d_in[11];
    const float* ao1   = (const float*)d_in[12];
    const float* dWp   = (const float*)d_in[13];
    const float* dW0p  = (const float*)d_in[14];
    const float* dW1p  = (const float*)d_in[15];
    const float* dW01p = (const float*)d_in[16];
    const float* dW2p  = (const float*)d_in[17];
    const float* dW02p = (const float*)d_in[18];
    const float* dVp   = (const float*)d_in[19];
    const float* dV0p  = (const float*)d_in[20];
    float* outp = (float*)d_out;

    char* ws = (char*)d_ws;
    auto alloc = [&](size_t bytes) {
        char* p = ws;
        ws += (bytes + 255) & ~(size_t)255;
        return p;
    };
    bf* hin     = (bf*)alloc((size_t)N * F * 2);
    bf* whA     = (bf*)alloc((size_t)H * N * D1 * 2);
    bf* hb      = (bf*)alloc((size_t)H * N * D1 * 2);
    bf* hcat    = (bf*)alloc((size_t)N * H * D1 * 2);
    bf* o1Wh    = (bf*)alloc((size_t)N * O1 * 2);
    bf* o1o     = (bf*)alloc((size_t)N * O1 * 2);
    bf* o2Wh    = (bf*)alloc((size_t)N * 2);
    bf* o2o     = (bf*)alloc((size_t)N * 2);
    bf* Wh0t    = (bf*)alloc((size_t)H * F * D1 * 2);
    bf* Wh1t    = (bf*)alloc((size_t)H * D1 * D1 * 2);
    bf* Wo0t    = (bf*)alloc((size_t)H * D1 * O1 * 2);
    int elerN = 4 * H * N + 2 * N;
    float* elerZ = (float*)alloc((size_t)elerN * 4);
    float* el1 = elerZ;
    float* er1 = el1 + H * N;
    float* el2 = er1 + H * N;
    float* er2 = el2 + H * N;
    float* el3 = er2 + H * N;
    float* er3 = el3 + N;
    float* el4 = (float*)alloc((size_t)N * 4);
    float* er4 = (float*)alloc((size_t)N * 4);
    float* dv  = (float*)alloc((size_t)N * 4);
    int* colIdx = (int*)alloc((size_t)N * MAXDEG * 4);
    int* deg    = (int*)alloc((size_t)N * 4);

    zero_f32<<<(elerN + 255) / 256, 256, 0, stream>>>(elerZ, elerN);
    csr_rowsum<<<N, 256, 0, stream>>>(adj, s_mat, colIdx, deg, dv, N);
    {
        const int totalPrep = N * F + H * F * D1 + H * D1 * D1 + H * D1 * O1;
        prep<<<(totalPrep + 255) / 256, 256, 0, stream>>>(
            x, obs, theta, Wh0, Wh1, Wo0, hin, Wh0t, Wh1t, Wo0t);
    }

    // ----- multi-head layer 1 (D=256, elu) -----
    gemm_mfma128<<<dim3(D1 / 128, N / 128, H), 256, 0, stream>>>(
        hin, Wh0t, whA, N, F, D1, 0, (size_t)D1 * F, (size_t)N * D1,
        ah0, (size_t)2 * D1, el1, er1);
    attn_vec<256, 1, 4><<<N * H, 256, 0, stream>>>(
        (const unsigned short*)whA, el1, er1, colIdx, deg, hb,
        N, (size_t)N * D1, (size_t)N * D1, D1);

    // ----- multi-head layer 2 (D=256, elu) -> hcat interleaved -----
    gemm_mfma128<<<dim3(D1 / 128, N / 128, H), 256, 0, stream>>>(
        hb, Wh1t, whA, N, D1, D1, (size_t)N * D1, (size_t)D1 * D1, (size_t)N * D1,
        ah1, (size_t)2 * D1, el2, er2);
    attn_vec<256, 1, 4><<<N * H, 256, 0, stream>>>(
        (const unsigned short*)whA, el2, er2, colIdx, deg, hcat,
        N, (size_t)N * D1, (size_t)D1, H * D1);

    // ----- output layer 1 (D=64, no act) -----
    gemm_mfma64<<<dim3(O1 / 64, N / 64, 1), 256, 0, stream>>>(
        hcat, Wo0t, o1Wh, N, H * D1, O1, 0, 0, 0,
        ao0, 0, el3, er3);
    attn_vec<64, 0, 1><<<N, 256, 0, stream>>>(
        (const unsigned short*)o1Wh, el3, er3, colIdx, deg, o1o, N, 0, 0, O1);

    // ----- output layer 2 (D=1, no act) -----
    matvec64_kernel<<<N, 64, 0, stream>>>(o1o, Wo1, ao1, o2Wh, el4, er4, N);
    attn_d1<<<N, 256, 0, stream>>>(o2Wh, el4, er4, colIdx, deg, o2o, N);

    // ----- elu + degreeNN -----
    degree_nn<<<(N + 255) / 256, 256, 0, stream>>>(o2o, dv, dWp, dW0p, dW1p,
        dW01p, dW2p, dW02p, dVp, dV0p, outp, N);
}

// Round 7
// 410.975 us; speedup vs baseline: 1.2252x; 1.0410x over previous
//
#include <hip/hip_runtime.h>
#include <hip/hip_bf16.h>
#include <math.h>

#define MAXDEG 512

typedef short v8s __attribute__((ext_vector_type(8)));
typedef float v4f __attribute__((ext_vector_type(4)));
typedef float v2f __attribute__((ext_vector_type(2)));
typedef __hip_bfloat16 bf;

// ---------------- block reduce helpers ----------------
__device__ __forceinline__ float blockReduceSum(float v) {
    __shared__ float sh[8];
    int lane = threadIdx.x & 63, w = threadIdx.x >> 6;
    for (int o = 32; o > 0; o >>= 1) v += __shfl_down(v, o);
    __syncthreads();
    if (lane == 0) sh[w] = v;
    __syncthreads();
    if (w == 0) {
        int nw = (blockDim.x + 63) >> 6;
        v = (lane < nw) ? sh[lane] : 0.f;
        for (int o = 4; o > 0; o >>= 1) v += __shfl_down(v, o);
        if (lane == 0) sh[0] = v;
    }
    __syncthreads();
    return sh[0];
}

__device__ __forceinline__ float blockReduceMax(float v) {
    __shared__ float sh[8];
    int lane = threadIdx.x & 63, w = threadIdx.x >> 6;
    for (int o = 32; o > 0; o >>= 1) v = fmaxf(v, __shfl_down(v, o));
    __syncthreads();
    if (lane == 0) sh[w] = v;
    __syncthreads();
    if (w == 0) {
        int nw = (blockDim.x + 63) >> 6;
        v = (lane < nw) ? sh[lane] : -3.4e38f;
        for (int o = 4; o > 0; o >>= 1) v = fmaxf(v, __shfl_down(v, o));
        if (lane == 0) sh[0] = v;
    }
    __syncthreads();
    return sh[0];
}

// Fast bf16x2 -> f32x2: lo needs the shift; hi is a free reinterpret (the
// junk low-16 mantissa bits add <=1 bf16-ulp, far inside the tolerance).
__device__ __forceinline__ v2f bf2f_fast(unsigned int u) {
    union { unsigned int u; float f; } lo, hi;
    lo.u = u << 16;
    hi.u = u;
    return (v2f){lo.f, hi.f};
}

__device__ __forceinline__ void acc_add(v2f* a, float p, const uint4& r) {
    v2f pp = (v2f){p, p};
    a[0] += pp * bf2f_fast(r.x);
    a[1] += pp * bf2f_fast(r.y);
    a[2] += pp * bf2f_fast(r.z);
    a[3] += pp * bf2f_fast(r.w);
}

// ---------------- kernels ----------------

// CSR build + s_mat row sum in one float4-vectorized pass.
__global__ void csr_rowsum(const float* __restrict__ adj, const float* __restrict__ s,
                           int* __restrict__ colIdx, int* __restrict__ deg,
                           float* __restrict__ dv, int N) {
    int row = blockIdx.x;
    __shared__ int cnt;
    if (threadIdx.x == 0) cnt = 0;
    __syncthreads();
    const float4* ar = (const float4*)(adj + (size_t)row * N);
    const float4* sr = (const float4*)(s + (size_t)row * N);
    int* outp = colIdx + (size_t)row * MAXDEG;
    float psum = 0.f;
    const int n4 = N >> 2;
    for (int j4 = threadIdx.x; j4 < n4; j4 += blockDim.x) {
        float4 a4 = ar[j4];
        float4 s4 = sr[j4];
        psum += (s4.x + s4.y) + (s4.z + s4.w);
        int jb = j4 << 2;
        if (a4.x > 0.f) { int p = atomicAdd(&cnt, 1); if (p < MAXDEG) outp[p] = jb; }
        if (a4.y > 0.f) { int p = atomicAdd(&cnt, 1); if (p < MAXDEG) outp[p] = jb + 1; }
        if (a4.z > 0.f) { int p = atomicAdd(&cnt, 1); if (p < MAXDEG) outp[p] = jb + 2; }
        if (a4.w > 0.f) { int p = atomicAdd(&cnt, 1); if (p < MAXDEG) outp[p] = jb + 3; }
    }
    psum = blockReduceSum(psum);
    __syncthreads();
    if (threadIdx.x == 0) {
        deg[row] = cnt < MAXDEG ? cnt : MAXDEG;
        dv[row] = psum;
    }
}

// hin (x + seed*theta -> bf16) + three weight transposes + el/er zeroing.
__global__ void prep(const float* __restrict__ x, const int* __restrict__ obs,
                     const float* __restrict__ theta,
                     const float* __restrict__ Wh0, const float* __restrict__ Wh1,
                     const float* __restrict__ Wo0,
                     bf* __restrict__ hin, bf* __restrict__ Wh0t,
                     bf* __restrict__ Wh1t, bf* __restrict__ Wo0t,
                     float* __restrict__ elerZ, int elerN) {
    const int n0 = 4096 * 512;       // hin
    const int n1 = 4 * 512 * 256;    // Wh0t
    const int n2 = 4 * 256 * 256;    // Wh1t
    const int n3 = 1024 * 64;        // Wo0t
    int i = blockIdx.x * 256 + threadIdx.x;
    if (i < n0) {
        int n = i >> 9, f = i & 511;
        float v = x[i];
        if (obs[n] == 1) v += theta[f];
        hin[i] = __float2bfloat16(v);
    } else if (i < n0 + n1) {
        int t = i - n0;                         // [b][m<256][k<512]
        int b = t / (512 * 256), r = t % (512 * 256);
        int mm = r >> 9, kk = r & 511;
        Wh0t[t] = __float2bfloat16(Wh0[b * 512 * 256 + kk * 256 + mm]);
    } else if (i < n0 + n1 + n2) {
        int t = i - n0 - n1;                    // [b][m<256][k<256]
        int b = t >> 16, r = t & 65535;
        int mm = r >> 8, kk = r & 255;
        Wh1t[t] = __float2bfloat16(Wh1[b * 65536 + kk * 256 + mm]);
    } else if (i < n0 + n1 + n2 + n3) {
        int t = i - n0 - n1 - n2;               // [m<64][k<1024]
        int mm = t >> 10, kk = t & 1023;
        Wo0t[t] = __float2bfloat16(Wo0[kk * 64 + mm]);
    } else if (i < n0 + n1 + n2 + n3 + elerN) {
        elerZ[i - n0 - n1 - n2 - n3] = 0.f;
    }
}

// 128x128 block-tile MFMA GEMM: C[b] = A[b] @ Bt[b]^T (bf16 out) with fused
// el/er epilogue (atomicAdd partials). N%128==0, M%128==0, K%32==0.
__global__ __launch_bounds__(256) void gemm_mfma128(
    const bf* __restrict__ A, const bf* __restrict__ Bt,
    bf* __restrict__ C, int N, int K, int M,
    size_t sA, size_t sB, size_t sC,
    const float* __restrict__ aVec, size_t aStride,
    float* __restrict__ el, float* __restrict__ er) {
    int b = blockIdx.z;
    const unsigned short* Ag = (const unsigned short*)(A + (size_t)b * sA);
    const unsigned short* Bg = (const unsigned short*)(Bt + (size_t)b * sB);
    bf* Cg = C + (size_t)b * sC;
    const float* av = aVec + (size_t)b * aStride;

    __shared__ __align__(16) unsigned short As[128][40];
    __shared__ __align__(16) unsigned short Bs[128][40];

    const int tid = threadIdx.x;
    const int wave = tid >> 6, lane = tid & 63;
    const int wm = wave >> 1, wn = wave & 1;
    const int row0 = blockIdx.y * 128, col0 = blockIdx.x * 128;
    const int lr = tid >> 2;
    const int lo = (tid & 3) * 8;
    const int m = lane & 15, quad = lane >> 4;

    v4f acc[4][4];
    #pragma unroll
    for (int i = 0; i < 4; i++)
        #pragma unroll
        for (int c = 0; c < 4; c++) acc[i][c] = (v4f)(0.f);

    for (int k0 = 0; k0 < K; k0 += 32) {
        *(int4*)(&As[lr][lo]) =
            *(const int4*)(Ag + (size_t)(row0 + lr) * K + k0 + lo);
        *(int4*)(&As[lr + 64][lo]) =
            *(const int4*)(Ag + (size_t)(row0 + 64 + lr) * K + k0 + lo);
        *(int4*)(&Bs[lr][lo]) =
            *(const int4*)(Bg + (size_t)(col0 + lr) * K + k0 + lo);
        *(int4*)(&Bs[lr + 64][lo]) =
            *(const int4*)(Bg + (size_t)(col0 + 64 + lr) * K + k0 + lo);
        __syncthreads();
        v8s af[4], bfv[4];
        #pragma unroll
        for (int i = 0; i < 4; i++)
            af[i] = *(const v8s*)(&As[wm * 64 + i * 16 + m][quad * 8]);
        #pragma unroll
        for (int c = 0; c < 4; c++)
            bfv[c] = *(const v8s*)(&Bs[wn * 64 + c * 16 + m][quad * 8]);
        #pragma unroll
        for (int i = 0; i < 4; i++)
            #pragma unroll
            for (int c = 0; c < 4; c++)
                acc[i][c] = __builtin_amdgcn_mfma_f32_16x16x32_bf16(
                    af[i], bfv[c], acc[i][c], 0, 0, 0);
        __syncthreads();
    }
    #pragma unroll
    for (int i = 0; i < 4; i++)
        #pragma unroll
        for (int c = 0; c < 4; c++)
            #pragma unroll
            for (int r = 0; r < 4; r++) {
                int row = row0 + wm * 64 + i * 16 + quad * 4 + r;
                int col = col0 + wn * 64 + c * 16 + m;
                Cg[(size_t)row * M + col] = __float2bfloat16(acc[i][c][r]);
            }
    float ael[4], aer[4];
    #pragma unroll
    for (int c = 0; c < 4; c++) {
        ael[c] = av[col0 + wn * 64 + c * 16 + m];
        aer[c] = av[M + col0 + wn * 64 + c * 16 + m];
    }
    #pragma unroll
    for (int i = 0; i < 4; i++)
        #pragma unroll
        for (int r = 0; r < 4; r++) {
            float pel = 0.f, per_ = 0.f;
            #pragma unroll
            for (int c = 0; c < 4; c++) {
                pel += acc[i][c][r] * ael[c];
                per_ += acc[i][c][r] * aer[c];
            }
            #pragma unroll
            for (int off = 1; off < 16; off <<= 1) {
                pel += __shfl_xor(pel, off);
                per_ += __shfl_xor(per_, off);
            }
            if (m == 0) {
                int row = row0 + wm * 64 + i * 16 + quad * 4 + r;
                atomicAdd(&el[(size_t)b * N + row], pel);
                atomicAdd(&er[(size_t)b * N + row], per_);
            }
        }
}

// 64x64 tile GEMM (M=64 output layer), bf16 out, fused el/er.
__global__ __launch_bounds__(256) void gemm_mfma64(
    const bf* __restrict__ A, const bf* __restrict__ Bt,
    bf* __restrict__ C, int N, int K, int M,
    size_t sA, size_t sB, size_t sC,
    const float* __restrict__ aVec, size_t aStride,
    float* __restrict__ el, float* __restrict__ er) {
    int b = blockIdx.z;
    const unsigned short* Ag = (const unsigned short*)(A + (size_t)b * sA);
    const unsigned short* Bg = (const unsigned short*)(Bt + (size_t)b * sB);
    bf* Cg = C + (size_t)b * sC;
    const float* av = aVec + (size_t)b * aStride;

    __shared__ __align__(16) unsigned short As[64][40];
    __shared__ __align__(16) unsigned short Bs[64][40];

    const int tid = threadIdx.x;
    const int wave = tid >> 6, lane = tid & 63;
    const int row0 = blockIdx.y * 64, col0 = blockIdx.x * 64;
    const int sRow = tid >> 2;
    const int sOff = (tid & 3) * 8;
    const int m = lane & 15, quad = lane >> 4;

    v4f acc[4];
    #pragma unroll
    for (int c = 0; c < 4; c++) acc[c] = (v4f)(0.f);

    for (int k0 = 0; k0 < K; k0 += 32) {
        *(int4*)(&As[sRow][sOff]) =
            *(const int4*)(Ag + (size_t)(row0 + sRow) * K + k0 + sOff);
        *(int4*)(&Bs[sRow][sOff]) =
            *(const int4*)(Bg + (size_t)(col0 + sRow) * K + k0 + sOff);
        __syncthreads();
        v8s af = *(const v8s*)(&As[wave * 16 + m][quad * 8]);
        #pragma unroll
        for (int c = 0; c < 4; c++) {
            v8s bfv = *(const v8s*)(&Bs[c * 16 + m][quad * 8]);
            acc[c] = __builtin_amdgcn_mfma_f32_16x16x32_bf16(af, bfv, acc[c], 0, 0, 0);
        }
        __syncthreads();
    }
    #pragma unroll
    for (int c = 0; c < 4; c++)
        #pragma unroll
        for (int r = 0; r < 4; r++) {
            int row = row0 + wave * 16 + quad * 4 + r;
            int col = col0 + c * 16 + m;
            Cg[(size_t)row * M + col] = __float2bfloat16(acc[c][r]);
        }
    float ael[4], aer[4];
    #pragma unroll
    for (int c = 0; c < 4; c++) {
        ael[c] = av[col0 + c * 16 + m];
        aer[c] = av[M + col0 + c * 16 + m];
    }
    #pragma unroll
    for (int r = 0; r < 4; r++) {
        float pel = 0.f, per_ = 0.f;
        #pragma unroll
        for (int c = 0; c < 4; c++) {
            pel += acc[c][r] * ael[c];
            per_ += acc[c][r] * aer[c];
        }
        #pragma unroll
        for (int off = 1; off < 16; off <<= 1) {
            pel += __shfl_xor(pel, off);
            per_ += __shfl_xor(per_, off);
        }
        if (m == 0) {
            int row = row0 + wave * 16 + quad * 4 + r;
            atomicAdd(&el[(size_t)b * N + row], pel);
            atomicAdd(&er[(size_t)b * N + row], per_);
        }
    }
}

// Masked softmax + bf16 gather (L2-resident). Lane covers 8 dims (uint4).
// Offsets j*D precomputed; list padded with p=0 entries; hi-half reinterpret
// unpack (4 shifts per uint4 instead of 8 shift+mask).
// HEADS==4: XCD clustering (head h -> blocks with blk%8 in {2h,2h+1}).
template<int D, int ACT, int HEADS>
__global__ __launch_bounds__(256) void attn_vec(
    const unsigned short* __restrict__ Wh, const float* __restrict__ el,
    const float* __restrict__ er, const int* __restrict__ colIdx,
    const int* __restrict__ deg, bf* __restrict__ out,
    int N, size_t sWh, size_t sOut, int outRowStride) {
    constexpr int LPN = D / 8;
    constexpr int NPW = 64 / LPN;
    constexpr int STRIDE = 4 * NPW;
    constexpr int PAD = 2 * STRIDE;

    int b, row;
    if (HEADS == 4) {
        int blk = blockIdx.x;
        b = (blk & 7) >> 1;
        row = ((blk >> 3) << 1) | (blk & 1);
    } else {
        b = 0;
        row = blockIdx.x;
    }
    const int tid = threadIdx.x;
    const unsigned short* whb = Wh + (size_t)b * sWh;
    const float* erb = er + (size_t)b * N;
    const float eln = el[(size_t)b * N + row];
    const int dc = deg[row];
    const int dcp = (dc + PAD - 1) & ~(PAD - 1);
    const int* ci = colIdx + (size_t)row * MAXDEG;

    __shared__ __align__(16) float2 spc[MAXDEG];  // {p, asint(j*D)}
    __shared__ __align__(16) float redc[4 * D];

    float mx = -3.4e38f;
    for (int k = tid; k < dc; k += 256) {
        int j = ci[k];
        float s = eln + erb[j];
        s = fmaxf(s, 0.2f * s);               // LeakyReLU(0.2)
        spc[k] = make_float2(s, __int_as_float(j * D));
        mx = fmaxf(mx, s);
    }
    for (int k = dc + tid; k < dcp; k += 256)
        spc[k] = make_float2(0.f, __int_as_float(0));
    mx = blockReduceMax(mx);
    float l = 0.f;
    for (int k = tid; k < dc; k += 256) {
        float p = __expf(spc[k].x - mx);
        spc[k].x = p;
        l += p;
    }
    l = blockReduceSum(l);
    const float inv = 1.f / l;

    const int wave = tid >> 6, lane = tid & 63;
    const int sub = lane / LPN;
    const int dl = (lane % LPN) * 8;
    const unsigned short* wp = whb + dl;

    v2f a0[4], a1[4];
    #pragma unroll
    for (int i = 0; i < 4; i++) { a0[i] = (v2f)(0.f); a1[i] = (v2f)(0.f); }

    for (int k = wave * NPW + sub; k < dcp; k += 2 * STRIDE) {
        float2 pc0 = spc[k];
        float2 pc1 = spc[k + STRIDE];
        const uint4 r0 = *(const uint4*)(wp + __float_as_int(pc0.y));
        const uint4 r1 = *(const uint4*)(wp + __float_as_int(pc1.y));
        acc_add(a0, pc0.x, r0);
        acc_add(a1, pc1.x, r1);
    }
    #pragma unroll
    for (int i = 0; i < 4; i++) a0[i] += a1[i];
    #pragma unroll
    for (int off = LPN; off < 64; off <<= 1)
        #pragma unroll
        for (int i = 0; i < 4; i++) {
            a0[i][0] += __shfl_xor(a0[i][0], off);
            a0[i][1] += __shfl_xor(a0[i][1], off);
        }
    __syncthreads();
    if (sub == 0)
        #pragma unroll
        for (int i = 0; i < 4; i++)
            *(float2*)(&redc[wave * D + dl + 2 * i]) = make_float2(a0[i][0], a0[i][1]);
    __syncthreads();
    if (tid < D) {
        float v = (redc[tid] + redc[D + tid] + redc[2 * D + tid] + redc[3 * D + tid]) * inv;
        if (ACT == 1) v = (v > 0.f) ? v : expm1f(v);   // ELU
        out[(size_t)b * sOut + (size_t)row * outRowStride + tid] = __float2bfloat16(v);
    }
}

// D==1 attention (output layer 2)
__global__ void attn_d1(const bf* __restrict__ Wh, const float* __restrict__ el,
                        const float* __restrict__ er, const int* __restrict__ colIdx,
                        const int* __restrict__ deg, bf* __restrict__ out, int N) {
    int row = blockIdx.x, tid = threadIdx.x;
    const float eln = el[row];
    const int dc = deg[row];
    const int* ci = colIdx + (size_t)row * MAXDEG;
    __shared__ float sp[MAXDEG];
    __shared__ int sc[MAXDEG];
    float mx = -3.4e38f;
    for (int k = tid; k < dc; k += blockDim.x) {
        int j = ci[k];
        sc[k] = j;
        float s = eln + er[j];
        s = fmaxf(s, 0.2f * s);
        sp[k] = s;
        mx = fmaxf(mx, s);
    }
    mx = blockReduceMax(mx);
    float l = 0.f, acc = 0.f;
    for (int k = tid; k < dc; k += blockDim.x) {
        float p = __expf(sp[k] - mx);
        l += p;
        acc += p * __bfloat162float(Wh[sc[k]]);
    }
    l = blockReduceSum(l);
    acc = blockReduceSum(acc);
    if (tid == 0) out[row] = __float2bfloat16(acc / l);
}

// o2Wh[n] = o1o[n,:64]·Wo1[:,0]; fused el4/er4 = o2Wh*ao1[0/1]
__global__ void matvec64_kernel(const bf* __restrict__ h3,
                                const float* __restrict__ w,
                                const float* __restrict__ ao1,
                                bf* __restrict__ out,
                                float* __restrict__ el4, float* __restrict__ er4, int N) {
    int row = blockIdx.x;
    float v = __bfloat162float(h3[(size_t)row * 64 + threadIdx.x]) * w[threadIdx.x];
    for (int o = 32; o > 0; o >>= 1) v += __shfl_down(v, o);
    if (threadIdx.x == 0) {
        out[row] = __float2bfloat16(v);
        el4[row] = v * ao1[0];
        er4[row] = v * ao1[1];
    }
}

__device__ __forceinline__ float leaky(float x) { return x >= 0.f ? x : 0.2f * x; }

__global__ void degree_nn(const bf* __restrict__ h4, const float* __restrict__ dv,
                          const float* __restrict__ dW, const float* __restrict__ dW0,
                          const float* __restrict__ dW1, const float* __restrict__ dW01,
                          const float* __restrict__ dW2, const float* __restrict__ dW02,
                          const float* __restrict__ dV, const float* __restrict__ dV0,
                          float* __restrict__ out, int N) {
    int n = blockIdx.x * blockDim.x + threadIdx.x;
    if (n >= N) return;
    float h = __bfloat162float(h4[n]);
    h = (h > 0.f) ? h : expm1f(h);            // elu
    float d = dv[n];
    float t0[10], t1[20], t2[10];
    #pragma unroll
    for (int i = 0; i < 10; i++)
        t0[i] = leaky(h * dW[i] + d * dW[10 + i] + dW0[i]);
    #pragma unroll
    for (int j = 0; j < 20; j++) {
        float s = dW01[j];
        #pragma unroll
        for (int i = 0; i < 10; i++) s += t0[i] * dW1[i * 20 + j];
        t1[j] = leaky(s);
    }
    #pragma unroll
    for (int j = 0; j < 10; j++) {
        float s = dW02[j];
        #pragma unroll
        for (int i = 0; i < 20; i++) s += t1[i] * dW2[i * 10 + j];
        t2[j] = leaky(s);
    }
    float o = dV0[0];
    #pragma unroll
    for (int i = 0; i < 10; i++) o += t2[i] * dV[i];
    out[n] = leaky(o);
}

// ---------------- launch ----------------
extern "C" void kernel_launch(void* const* d_in, const int* in_sizes, int n_in,
                              void* d_out, int out_size, void* d_ws, size_t ws_size,
                              hipStream_t stream) {
    const int N = 4096, F = 512, H = 4, D1 = 256, O1 = 64;
    const float* x     = (const float*)d_in[0];
    const float* adj   = (const float*)d_in[1];
    const int*   obs   = (const int*)  d_in[2];
    const float* s_mat = (const float*)d_in[3];
    const float* theta = (const float*)d_in[4];
    const float* Wh0   = (const float*)d_in[5];
    const float* ah0   = (const float*)d_in[6];
    const float* Wh1   = (const float*)d_in[7];
    const float* ah1   = (const float*)d_in[8];
    const float* Wo0   = (const float*)d_in[9];
    const float* ao0   = (const float*)d_in[10];
    const float* Wo1   = (const float*)d_in[11];
    const float* ao1   = (const float*)d_in[12];
    const float* dWp   = (const float*)d_in[13];
    const float* dW0p  = (const float*)d_in[14];
    const float* dW1p  = (const float*)d_in[15];
    const float* dW01p = (const float*)d_in[16];
    const float* dW2p  = (const float*)d_in[17];
    const float* dW02p = (const float*)d_in[18];
    const float* dVp   = (const float*)d_in[19];
    const float* dV0p  = (const float*)d_in[20];
    float* outp = (float*)d_out;

    char* ws = (char*)d_ws;
    auto alloc = [&](size_t bytes) {
        char* p = ws;
        ws += (bytes + 255) & ~(size_t)255;
        return p;
    };
    bf* hin     = (bf*)alloc((size_t)N * F * 2);
    bf* whA     = (bf*)alloc((size_t)H * N * D1 * 2);
    bf* hb      = (bf*)alloc((size_t)H * N * D1 * 2);
    bf* hcat    = (bf*)alloc((size_t)N * H * D1 * 2);
    bf* o1Wh    = (bf*)alloc((size_t)N * O1 * 2);
    bf* o1o     = (bf*)alloc((size_t)N * O1 * 2);
    bf* o2Wh    = (bf*)alloc((size_t)N * 2);
    bf* o2o     = (bf*)alloc((size_t)N * 2);
    bf* Wh0t    = (bf*)alloc((size_t)H * F * D1 * 2);
    bf* Wh1t    = (bf*)alloc((size_t)H * D1 * D1 * 2);
    bf* Wo0t    = (bf*)alloc((size_t)H * D1 * O1 * 2);
    int elerN = 4 * H * N + 2 * N;
    float* elerZ = (float*)alloc((size_t)elerN * 4);
    float* el1 = elerZ;
    float* er1 = el1 + H * N;
    float* el2 = er1 + H * N;
    float* er2 = el2 + H * N;
    float* el3 = er2 + H * N;
    float* er3 = el3 + N;
    float* el4 = (float*)alloc((size_t)N * 4);
    float* er4 = (float*)alloc((size_t)N * 4);
    float* dv  = (float*)alloc((size_t)N * 4);
    int* colIdx = (int*)alloc((size_t)N * MAXDEG * 4);
    int* deg    = (int*)alloc((size_t)N * 4);

    {
        const int totalPrep = N * F + H * F * D1 + H * D1 * D1 + H * D1 * O1 + elerN;
        prep<<<(totalPrep + 255) / 256, 256, 0, stream>>>(
            x, obs, theta, Wh0, Wh1, Wo0, hin, Wh0t, Wh1t, Wo0t, elerZ, elerN);
    }
    csr_rowsum<<<N, 256, 0, stream>>>(adj, s_mat, colIdx, deg, dv, N);

    // ----- multi-head layer 1 (D=256, elu) -----
    gemm_mfma128<<<dim3(D1 / 128, N / 128, H), 256, 0, stream>>>(
        hin, Wh0t, whA, N, F, D1, 0, (size_t)D1 * F, (size_t)N * D1,
        ah0, (size_t)2 * D1, el1, er1);
    attn_vec<256, 1, 4><<<N * H, 256, 0, stream>>>(
        (const unsigned short*)whA, el1, er1, colIdx, deg, hb,
        N, (size_t)N * D1, (size_t)N * D1, D1);

    // ----- multi-head layer 2 (D=256, elu) -> hcat interleaved -----
    gemm_mfma128<<<dim3(D1 / 128, N / 128, H), 256, 0, stream>>>(
        hb, Wh1t, whA, N, D1, D1, (size_t)N * D1, (size_t)D1 * D1, (size_t)N * D1,
        ah1, (size_t)2 * D1, el2, er2);
    attn_vec<256, 1, 4><<<N * H, 256, 0, stream>>>(
        (const unsigned short*)whA, el2, er2, colIdx, deg, hcat,
        N, (size_t)N * D1, (size_t)D1, H * D1);

    // ----- output layer 1 (D=64, no act) -----
    gemm_mfma64<<<dim3(O1 / 64, N / 64, 1), 256, 0, stream>>>(
        hcat, Wo0t, o1Wh, N, H * D1, O1, 0, 0, 0,
        ao0, 0, el3, er3);
    attn_vec<64, 0, 1><<<N, 256, 0, stream>>>(
        (const unsigned short*)o1Wh, el3, er3, colIdx, deg, o1o, N, 0, 0, O1);

    // ----- output layer 2 (D=1, no act) -----
    matvec64_kernel<<<N, 64, 0, stream>>>(o1o, Wo1, ao1, o2Wh, el4, er4, N);
    attn_d1<<<N, 256, 0, stream>>>(o2Wh, el4, er4, colIdx, deg, o2o, N);

    // ----- elu + degreeNN -----
    degree_nn<<<(N + 255) / 256, 256, 0, stream>>>(o2o, dv, dWp, dW0p, dW1p,
        dW01p, dW2p, dW02p, dVp, dV0p, outp, N);
}

// Round 8
// 403.443 us; speedup vs baseline: 1.2481x; 1.0187x over previous
//
#include <hip/hip_runtime.h>
#include <hip/hip_bf16.h>
#include <hip/hip_fp16.h>
#include <math.h>

#define MAXDEG 512

typedef short v8s __attribute__((ext_vector_type(8)));
typedef float v4f __attribute__((ext_vector_type(4)));
typedef _Float16 h2 __attribute__((ext_vector_type(2)));

// ---------------- block reduce helpers ----------------
__device__ __forceinline__ float blockReduceSum(float v) {
    __shared__ float sh[8];
    int lane = threadIdx.x & 63, w = threadIdx.x >> 6;
    for (int o = 32; o > 0; o >>= 1) v += __shfl_down(v, o);
    __syncthreads();
    if (lane == 0) sh[w] = v;
    __syncthreads();
    if (w == 0) {
        int nw = (blockDim.x + 63) >> 6;
        v = (lane < nw) ? sh[lane] : 0.f;
        for (int o = 4; o > 0; o >>= 1) v += __shfl_down(v, o);
        if (lane == 0) sh[0] = v;
    }
    __syncthreads();
    return sh[0];
}

__device__ __forceinline__ float blockReduceMax(float v) {
    __shared__ float sh[8];
    int lane = threadIdx.x & 63, w = threadIdx.x >> 6;
    for (int o = 32; o > 0; o >>= 1) v = fmaxf(v, __shfl_down(v, o));
    __syncthreads();
    if (lane == 0) sh[w] = v;
    __syncthreads();
    if (w == 0) {
        int nw = (blockDim.x + 63) >> 6;
        v = (lane < nw) ? sh[lane] : -3.4e38f;
        for (int o = 4; o > 0; o >>= 1) v = fmaxf(v, __shfl_down(v, o));
        if (lane == 0) sh[0] = v;
    }
    __syncthreads();
    return sh[0];
}

// ---------------- kernels ----------------

// CSR build + s_mat row sum in one float4-vectorized pass.
__global__ void csr_rowsum(const float* __restrict__ adj, const float* __restrict__ s,
                           int* __restrict__ colIdx, int* __restrict__ deg,
                           float* __restrict__ dv, int N) {
    int row = blockIdx.x;
    __shared__ int cnt;
    if (threadIdx.x == 0) cnt = 0;
    __syncthreads();
    const float4* ar = (const float4*)(adj + (size_t)row * N);
    const float4* sr = (const float4*)(s + (size_t)row * N);
    int* outp = colIdx + (size_t)row * MAXDEG;
    float psum = 0.f;
    const int n4 = N >> 2;
    for (int j4 = threadIdx.x; j4 < n4; j4 += blockDim.x) {
        float4 a4 = ar[j4];
        float4 s4 = sr[j4];
        psum += (s4.x + s4.y) + (s4.z + s4.w);
        int jb = j4 << 2;
        if (a4.x > 0.f) { int p = atomicAdd(&cnt, 1); if (p < MAXDEG) outp[p] = jb; }
        if (a4.y > 0.f) { int p = atomicAdd(&cnt, 1); if (p < MAXDEG) outp[p] = jb + 1; }
        if (a4.z > 0.f) { int p = atomicAdd(&cnt, 1); if (p < MAXDEG) outp[p] = jb + 2; }
        if (a4.w > 0.f) { int p = atomicAdd(&cnt, 1); if (p < MAXDEG) outp[p] = jb + 3; }
    }
    psum = blockReduceSum(psum);
    __syncthreads();
    if (threadIdx.x == 0) {
        deg[row] = cnt < MAXDEG ? cnt : MAXDEG;
        dv[row] = psum;
    }
}

// hin (x + seed*theta -> fp16) + three weight transposes (fp16) + el/er zeroing.
__global__ void prep(const float* __restrict__ x, const int* __restrict__ obs,
                     const float* __restrict__ theta,
                     const float* __restrict__ Wh0, const float* __restrict__ Wh1,
                     const float* __restrict__ Wo0,
                     __half* __restrict__ hin, __half* __restrict__ Wh0t,
                     __half* __restrict__ Wh1t, __half* __restrict__ Wo0t,
                     float* __restrict__ elerZ, int elerN) {
    const int n0 = 4096 * 512;       // hin
    const int n1 = 4 * 512 * 256;    // Wh0t
    const int n2 = 4 * 256 * 256;    // Wh1t
    const int n3 = 1024 * 64;        // Wo0t
    int i = blockIdx.x * 256 + threadIdx.x;
    if (i < n0) {
        int n = i >> 9, f = i & 511;
        float v = x[i];
        if (obs[n] == 1) v += theta[f];
        hin[i] = __float2half(v);
    } else if (i < n0 + n1) {
        int t = i - n0;                         // [b][m<256][k<512]
        int b = t / (512 * 256), r = t % (512 * 256);
        int mm = r >> 9, kk = r & 511;
        Wh0t[t] = __float2half(Wh0[b * 512 * 256 + kk * 256 + mm]);
    } else if (i < n0 + n1 + n2) {
        int t = i - n0 - n1;                    // [b][m<256][k<256]
        int b = t >> 16, r = t & 65535;
        int mm = r >> 8, kk = r & 255;
        Wh1t[t] = __float2half(Wh1[b * 65536 + kk * 256 + mm]);
    } else if (i < n0 + n1 + n2 + n3) {
        int t = i - n0 - n1 - n2;               // [m<64][k<1024]
        int mm = t >> 10, kk = t & 1023;
        Wo0t[t] = __float2half(Wo0[kk * 64 + mm]);
    } else if (i < n0 + n1 + n2 + n3 + elerN) {
        elerZ[i - n0 - n1 - n2 - n3] = 0.f;
    }
}

// 128x128 block-tile MFMA GEMM (fp16 in/out): C[b] = A[b] @ Bt[b]^T with
// fused el/er epilogue (atomicAdd partials). N%128==0, M%128==0, K%32==0.
__global__ __launch_bounds__(256) void gemm_mfma128(
    const __half* __restrict__ A, const __half* __restrict__ Bt,
    __half* __restrict__ C, int N, int K, int M,
    size_t sA, size_t sB, size_t sC,
    const float* __restrict__ aVec, size_t aStride,
    float* __restrict__ el, float* __restrict__ er) {
    int b = blockIdx.z;
    const unsigned short* Ag = (const unsigned short*)(A + (size_t)b * sA);
    const unsigned short* Bg = (const unsigned short*)(Bt + (size_t)b * sB);
    __half* Cg = C + (size_t)b * sC;
    const float* av = aVec + (size_t)b * aStride;

    __shared__ __align__(16) unsigned short As[128][40];
    __shared__ __align__(16) unsigned short Bs[128][40];

    const int tid = threadIdx.x;
    const int wave = tid >> 6, lane = tid & 63;
    const int wm = wave >> 1, wn = wave & 1;
    const int row0 = blockIdx.y * 128, col0 = blockIdx.x * 128;
    const int lr = tid >> 2;
    const int lo = (tid & 3) * 8;
    const int m = lane & 15, quad = lane >> 4;

    v4f acc[4][4];
    #pragma unroll
    for (int i = 0; i < 4; i++)
        #pragma unroll
        for (int c = 0; c < 4; c++) acc[i][c] = (v4f)(0.f);

    for (int k0 = 0; k0 < K; k0 += 32) {
        *(int4*)(&As[lr][lo]) =
            *(const int4*)(Ag + (size_t)(row0 + lr) * K + k0 + lo);
        *(int4*)(&As[lr + 64][lo]) =
            *(const int4*)(Ag + (size_t)(row0 + 64 + lr) * K + k0 + lo);
        *(int4*)(&Bs[lr][lo]) =
            *(const int4*)(Bg + (size_t)(col0 + lr) * K + k0 + lo);
        *(int4*)(&Bs[lr + 64][lo]) =
            *(const int4*)(Bg + (size_t)(col0 + 64 + lr) * K + k0 + lo);
        __syncthreads();
        v8s af[4], bfv[4];
        #pragma unroll
        for (int i = 0; i < 4; i++)
            af[i] = *(const v8s*)(&As[wm * 64 + i * 16 + m][quad * 8]);
        #pragma unroll
        for (int c = 0; c < 4; c++)
            bfv[c] = *(const v8s*)(&Bs[wn * 64 + c * 16 + m][quad * 8]);
        #pragma unroll
        for (int i = 0; i < 4; i++)
            #pragma unroll
            for (int c = 0; c < 4; c++)
                acc[i][c] = __builtin_amdgcn_mfma_f32_16x16x32_f16(
                    af[i], bfv[c], acc[i][c], 0, 0, 0);
        __syncthreads();
    }
    #pragma unroll
    for (int i = 0; i < 4; i++)
        #pragma unroll
        for (int c = 0; c < 4; c++)
            #pragma unroll
            for (int r = 0; r < 4; r++) {
                int row = row0 + wm * 64 + i * 16 + quad * 4 + r;
                int col = col0 + wn * 64 + c * 16 + m;
                Cg[(size_t)row * M + col] = __float2half(acc[i][c][r]);
            }
    float ael[4], aer[4];
    #pragma unroll
    for (int c = 0; c < 4; c++) {
        ael[c] = av[col0 + wn * 64 + c * 16 + m];
        aer[c] = av[M + col0 + wn * 64 + c * 16 + m];
    }
    #pragma unroll
    for (int i = 0; i < 4; i++)
        #pragma unroll
        for (int r = 0; r < 4; r++) {
            float pel = 0.f, per_ = 0.f;
            #pragma unroll
            for (int c = 0; c < 4; c++) {
                pel += acc[i][c][r] * ael[c];
                per_ += acc[i][c][r] * aer[c];
            }
            #pragma unroll
            for (int off = 1; off < 16; off <<= 1) {
                pel += __shfl_xor(pel, off);
                per_ += __shfl_xor(per_, off);
            }
            if (m == 0) {
                int row = row0 + wm * 64 + i * 16 + quad * 4 + r;
                atomicAdd(&el[(size_t)b * N + row], pel);
                atomicAdd(&er[(size_t)b * N + row], per_);
            }
        }
}

// 64x64 tile GEMM (M=64 output layer), fp16 in/out, fused el/er.
__global__ __launch_bounds__(256) void gemm_mfma64(
    const __half* __restrict__ A, const __half* __restrict__ Bt,
    __half* __restrict__ C, int N, int K, int M,
    size_t sA, size_t sB, size_t sC,
    const float* __restrict__ aVec, size_t aStride,
    float* __restrict__ el, float* __restrict__ er) {
    int b = blockIdx.z;
    const unsigned short* Ag = (const unsigned short*)(A + (size_t)b * sA);
    const unsigned short* Bg = (const unsigned short*)(Bt + (size_t)b * sB);
    __half* Cg = C + (size_t)b * sC;
    const float* av = aVec + (size_t)b * aStride;

    __shared__ __align__(16) unsigned short As[64][40];
    __shared__ __align__(16) unsigned short Bs[64][40];

    const int tid = threadIdx.x;
    const int wave = tid >> 6, lane = tid & 63;
    const int row0 = blockIdx.y * 64, col0 = blockIdx.x * 64;
    const int sRow = tid >> 2;
    const int sOff = (tid & 3) * 8;
    const int m = lane & 15, quad = lane >> 4;

    v4f acc[4];
    #pragma unroll
    for (int c = 0; c < 4; c++) acc[c] = (v4f)(0.f);

    for (int k0 = 0; k0 < K; k0 += 32) {
        *(int4*)(&As[sRow][sOff]) =
            *(const int4*)(Ag + (size_t)(row0 + sRow) * K + k0 + sOff);
        *(int4*)(&Bs[sRow][sOff]) =
            *(const int4*)(Bg + (size_t)(col0 + sRow) * K + k0 + sOff);
        __syncthreads();
        v8s af = *(const v8s*)(&As[wave * 16 + m][quad * 8]);
        #pragma unroll
        for (int c = 0; c < 4; c++) {
            v8s bfv = *(const v8s*)(&Bs[c * 16 + m][quad * 8]);
            acc[c] = __builtin_amdgcn_mfma_f32_16x16x32_f16(af, bfv, acc[c], 0, 0, 0);
        }
        __syncthreads();
    }
    #pragma unroll
    for (int c = 0; c < 4; c++)
        #pragma unroll
        for (int r = 0; r < 4; r++) {
            int row = row0 + wave * 16 + quad * 4 + r;
            int col = col0 + c * 16 + m;
            Cg[(size_t)row * M + col] = __float2half(acc[c][r]);
        }
    float ael[4], aer[4];
    #pragma unroll
    for (int c = 0; c < 4; c++) {
        ael[c] = av[col0 + c * 16 + m];
        aer[c] = av[M + col0 + c * 16 + m];
    }
    #pragma unroll
    for (int r = 0; r < 4; r++) {
        float pel = 0.f, per_ = 0.f;
        #pragma unroll
        for (int c = 0; c < 4; c++) {
            pel += acc[c][r] * ael[c];
            per_ += acc[c][r] * aer[c];
        }
        #pragma unroll
        for (int off = 1; off < 16; off <<= 1) {
            pel += __shfl_xor(pel, off);
            per_ += __shfl_xor(per_, off);
        }
        if (m == 0) {
            int row = row0 + wave * 16 + quad * 4 + r;
            atomicAdd(&el[(size_t)b * N + row], pel);
            atomicAdd(&er[(size_t)b * N + row], per_);
        }
    }
}

// Masked softmax + fp16 gather with packed-half accumulation (v_pk_fma_f16,
// zero unpack). spc holds {packed half2(p,p), byte offset j*D*2}. List padded
// with p=0 entries. HEADS==4: XCD clustering (head h -> blk%8 in {2h,2h+1}).
template<int D, int ACT, int HEADS>
__global__ __launch_bounds__(256) void attn_vec(
    const __half* __restrict__ Wh, const float* __restrict__ el,
    const float* __restrict__ er, const int* __restrict__ colIdx,
    const int* __restrict__ deg, __half* __restrict__ out,
    int N, size_t sWh, size_t sOut, int outRowStride) {
    constexpr int LPN = D / 8;        // lanes per neighbor (8 fp16 dims/lane)
    constexpr int NPW = 64 / LPN;     // neighbors per wave-step
    constexpr int STRIDE = 4 * NPW;   // neighbors per block-step
    constexpr int PAD = 2 * STRIDE;   // unroll-2 granularity

    int b, row;
    if (HEADS == 4) {
        int blk = blockIdx.x;
        b = (blk & 7) >> 1;
        row = ((blk >> 3) << 1) | (blk & 1);
    } else {
        b = 0;
        row = blockIdx.x;
    }
    const int tid = threadIdx.x;
    const __half* whb = Wh + (size_t)b * sWh;
    const float* erb = er + (size_t)b * N;
    const float eln = el[(size_t)b * N + row];
    const int dc = deg[row];
    const int dcp = (dc + PAD - 1) & ~(PAD - 1);
    const int* ci = colIdx + (size_t)row * MAXDEG;

    __shared__ __align__(16) float2 spc[MAXDEG];  // {score -> packed p, byte off}
    __shared__ __align__(16) float redc[4 * D];

    float mx = -3.4e38f;
    for (int k = tid; k < dc; k += 256) {
        int j = ci[k];
        float s = eln + erb[j];
        s = fmaxf(s, 0.2f * s);               // LeakyReLU(0.2)
        spc[k] = make_float2(s, __int_as_float(j * (D * 2)));
        mx = fmaxf(mx, s);
    }
    for (int k = dc + tid; k < dcp; k += 256)
        spc[k] = make_float2(__int_as_float(0), __int_as_float(0));
    mx = blockReduceMax(mx);
    float l = 0.f;
    for (int k = tid; k < dc; k += 256) {
        float p = __expf(spc[k].x - mx);
        l += p;
        unsigned int pu = __half_as_ushort(__float2half(p));
        spc[k].x = __int_as_float(pu | (pu << 16));   // packed half2 {p,p}
    }
    l = blockReduceSum(l);
    const float inv = 1.f / l;

    const int wave = tid >> 6, lane = tid & 63;
    const int sub = lane / LPN;
    const int dl = (lane % LPN) * 8;
    const char* wp = (const char*)(whb + dl);

    union HU { unsigned int u; h2 h; };
    union R4 { uint4 u; h2 h[4]; };

    h2 a0[4], a1[4];
    #pragma unroll
    for (int i = 0; i < 4; i++) { a0[i] = (h2)(_Float16)0; a1[i] = (h2)(_Float16)0; }

    for (int k = wave * NPW + sub; k < dcp; k += 2 * STRIDE) {
        float2 pc0 = spc[k];
        float2 pc1 = spc[k + STRIDE];
        R4 r0, r1;
        r0.u = *(const uint4*)(wp + __float_as_int(pc0.y));
        r1.u = *(const uint4*)(wp + __float_as_int(pc1.y));
        HU p0, p1;
        p0.u = __float_as_int(pc0.x);
        p1.u = __float_as_int(pc1.x);
        #pragma unroll
        for (int i = 0; i < 4; i++) {
            a0[i] += p0.h * r0.h[i];
            a1[i] += p1.h * r1.h[i];
        }
    }
    #pragma unroll
    for (int i = 0; i < 4; i++) a0[i] += a1[i];
    // cross-sub-group reduce on packed halves (bitcast through int shuffles)
    #pragma unroll
    for (int off = LPN; off < 64; off <<= 1)
        #pragma unroll
        for (int i = 0; i < 4; i++) {
            HU t, s;
            t.h = a0[i];
            s.u = __shfl_xor((int)t.u, off);
            a0[i] += s.h;
        }
    __syncthreads();
    if (sub == 0)
        #pragma unroll
        for (int i = 0; i < 4; i++) {
            redc[wave * D + dl + 2 * i]     = (float)a0[i][0];
            redc[wave * D + dl + 2 * i + 1] = (float)a0[i][1];
        }
    __syncthreads();
    if (tid < D) {
        float v = (redc[tid] + redc[D + tid] + redc[2 * D + tid] + redc[3 * D + tid]) * inv;
        if (ACT == 1) v = (v > 0.f) ? v : expm1f(v);   // ELU
        out[(size_t)b * sOut + (size_t)row * outRowStride + tid] = __float2half(v);
    }
}

// D==1 attention (output layer 2)
__global__ void attn_d1(const __half* __restrict__ Wh, const float* __restrict__ el,
                        const float* __restrict__ er, const int* __restrict__ colIdx,
                        const int* __restrict__ deg, __half* __restrict__ out, int N) {
    int row = blockIdx.x, tid = threadIdx.x;
    const float eln = el[row];
    const int dc = deg[row];
    const int* ci = colIdx + (size_t)row * MAXDEG;
    __shared__ float sp[MAXDEG];
    __shared__ int sc[MAXDEG];
    float mx = -3.4e38f;
    for (int k = tid; k < dc; k += blockDim.x) {
        int j = ci[k];
        sc[k] = j;
        float s = eln + er[j];
        s = fmaxf(s, 0.2f * s);
        sp[k] = s;
        mx = fmaxf(mx, s);
    }
    mx = blockReduceMax(mx);
    float l = 0.f, acc = 0.f;
    for (int k = tid; k < dc; k += blockDim.x) {
        float p = __expf(sp[k] - mx);
        l += p;
        acc += p * __half2float(Wh[sc[k]]);
    }
    l = blockReduceSum(l);
    acc = blockReduceSum(acc);
    if (tid == 0) out[row] = __float2half(acc / l);
}

// o2Wh[n] = o1o[n,:64]·Wo1[:,0]; fused el4/er4 = o2Wh*ao1[0/1]
__global__ void matvec64_kernel(const __half* __restrict__ h3,
                                const float* __restrict__ w,
                                const float* __restrict__ ao1,
                                __half* __restrict__ out,
                                float* __restrict__ el4, float* __restrict__ er4, int N) {
    int row = blockIdx.x;
    float v = __half2float(h3[(size_t)row * 64 + threadIdx.x]) * w[threadIdx.x];
    for (int o = 32; o > 0; o >>= 1) v += __shfl_down(v, o);
    if (threadIdx.x == 0) {
        out[row] = __float2half(v);
        el4[row] = v * ao1[0];
        er4[row] = v * ao1[1];
    }
}

__device__ __forceinline__ float leaky(float x) { return x >= 0.f ? x : 0.2f * x; }

__global__ void degree_nn(const __half* __restrict__ h4, const float* __restrict__ dv,
                          const float* __restrict__ dW, const float* __restrict__ dW0,
                          const float* __restrict__ dW1, const float* __restrict__ dW01,
                          const float* __restrict__ dW2, const float* __restrict__ dW02,
                          const float* __restrict__ dV, const float* __restrict__ dV0,
                          float* __restrict__ out, int N) {
    int n = blockIdx.x * blockDim.x + threadIdx.x;
    if (n >= N) return;
    float h = __half2float(h4[n]);
    h = (h > 0.f) ? h : expm1f(h);            // elu
    float d = dv[n];
    float t0[10], t1[20], t2[10];
    #pragma unroll
    for (int i = 0; i < 10; i++)
        t0[i] = leaky(h * dW[i] + d * dW[10 + i] + dW0[i]);
    #pragma unroll
    for (int j = 0; j < 20; j++) {
        float s = dW01[j];
        #pragma unroll
        for (int i = 0; i < 10; i++) s += t0[i] * dW1[i * 20 + j];
        t1[j] = leaky(s);
    }
    #pragma unroll
    for (int j = 0; j < 10; j++) {
        float s = dW02[j];
        #pragma unroll
        for (int i = 0; i < 20; i++) s += t1[i] * dW2[i * 10 + j];
        t2[j] = leaky(s);
    }
    float o = dV0[0];
    #pragma unroll
    for (int i = 0; i < 10; i++) o += t2[i] * dV[i];
    out[n] = leaky(o);
}

// ---------------- launch ----------------
extern "C" void kernel_launch(void* const* d_in, const int* in_sizes, int n_in,
                              void* d_out, int out_size, void* d_ws, size_t ws_size,
                              hipStream_t stream) {
    const int N = 4096, F = 512, H = 4, D1 = 256, O1 = 64;
    const float* x     = (const float*)d_in[0];
    const float* adj   = (const float*)d_in[1];
    const int*   obs   = (const int*)  d_in[2];
    const float* s_mat = (const float*)d_in[3];
    const float* theta = (const float*)d_in[4];
    const float* Wh0   = (const float*)d_in[5];
    const float* ah0   = (const float*)d_in[6];
    const float* Wh1   = (const float*)d_in[7];
    const float* ah1   = (const float*)d_in[8];
    const float* Wo0   = (const float*)d_in[9];
    const float* ao0   = (const float*)d_in[10];
    const float* Wo1   = (const float*)d_in[11];
    const float* ao1   = (const float*)d_in[12];
    const float* dWp   = (const float*)d_in[13];
    const float* dW0p  = (const float*)d_in[14];
    const float* dW1p  = (const float*)d_in[15];
    const float* dW01p = (const float*)d_in[16];
    const float* dW2p  = (const float*)d_in[17];
    const float* dW02p = (const float*)d_in[18];
    const float* dVp   = (const float*)d_in[19];
    const float* dV0p  = (const float*)d_in[20];
    float* outp = (float*)d_out;

    char* ws = (char*)d_ws;
    auto alloc = [&](size_t bytes) {
        char* p = ws;
        ws += (bytes + 255) & ~(size_t)255;
        return p;
    };
    __half* hin  = (__half*)alloc((size_t)N * F * 2);
    __half* whA  = (__half*)alloc((size_t)H * N * D1 * 2);
    __half* hb   = (__half*)alloc((size_t)H * N * D1 * 2);
    __half* hcat = (__half*)alloc((size_t)N * H * D1 * 2);
    __half* o1Wh = (__half*)alloc((size_t)N * O1 * 2);
    __half* o1o  = (__half*)alloc((size_t)N * O1 * 2);
    __half* o2Wh = (__half*)alloc((size_t)N * 2);
    __half* o2o  = (__half*)alloc((size_t)N * 2);
    __half* Wh0t = (__half*)alloc((size_t)H * F * D1 * 2);
    __half* Wh1t = (__half*)alloc((size_t)H * D1 * D1 * 2);
    __half* Wo0t = (__half*)alloc((size_t)H * D1 * O1 * 2);
    int elerN = 4 * H * N + 2 * N;
    float* elerZ = (float*)alloc((size_t)elerN * 4);
    float* el1 = elerZ;
    float* er1 = el1 + H * N;
    float* el2 = er1 + H * N;
    float* er2 = el2 + H * N;
    float* el3 = er2 + H * N;
    float* er3 = el3 + N;
    float* el4 = (float*)alloc((size_t)N * 4);
    float* er4 = (float*)alloc((size_t)N * 4);
    float* dv  = (float*)alloc((size_t)N * 4);
    int* colIdx = (int*)alloc((size_t)N * MAXDEG * 4);
    int* deg    = (int*)alloc((size_t)N * 4);

    {
        const int totalPrep = N * F + H * F * D1 + H * D1 * D1 + H * D1 * O1 + elerN;
        prep<<<(totalPrep + 255) / 256, 256, 0, stream>>>(
            x, obs, theta, Wh0, Wh1, Wo0, hin, Wh0t, Wh1t, Wo0t, elerZ, elerN);
    }
    csr_rowsum<<<N, 256, 0, stream>>>(adj, s_mat, colIdx, deg, dv, N);

    // ----- multi-head layer 1 (D=256, elu) -----
    gemm_mfma128<<<dim3(D1 / 128, N / 128, H), 256, 0, stream>>>(
        hin, Wh0t, whA, N, F, D1, 0, (size_t)D1 * F, (size_t)N * D1,
        ah0, (size_t)2 * D1, el1, er1);
    attn_vec<256, 1, 4><<<N * H, 256, 0, stream>>>(
        whA, el1, er1, colIdx, deg, hb,
        N, (size_t)N * D1, (size_t)N * D1, D1);

    // ----- multi-head layer 2 (D=256, elu) -> hcat interleaved -----
    gemm_mfma128<<<dim3(D1 / 128, N / 128, H), 256, 0, stream>>>(
        hb, Wh1t, whA, N, D1, D1, (size_t)N * D1, (size_t)D1 * D1, (size_t)N * D1,
        ah1, (size_t)2 * D1, el2, er2);
    attn_vec<256, 1, 4><<<N * H, 256, 0, stream>>>(
        whA, el2, er2, colIdx, deg, hcat,
        N, (size_t)N * D1, (size_t)D1, H * D1);

    // ----- output layer 1 (D=64, no act) -----
    gemm_mfma64<<<dim3(O1 / 64, N / 64, 1), 256, 0, stream>>>(
        hcat, Wo0t, o1Wh, N, H * D1, O1, 0, 0, 0,
        ao0, 0, el3, er3);
    attn_vec<64, 0, 1><<<N, 256, 0, stream>>>(
        o1Wh, el3, er3, colIdx, deg, o1o, N, 0, 0, O1);

    // ----- output layer 2 (D=1, no act) -----
    matvec64_kernel<<<N, 64, 0, stream>>>(o1o, Wo1, ao1, o2Wh, el4, er4, N);
    attn_d1<<<N, 256, 0, stream>>>(o2Wh, el4, er4, colIdx, deg, o2o, N);

    // ----- elu + degreeNN -----
    degree_nn<<<(N + 255) / 256, 256, 0, stream>>>(o2o, dv, dWp, dW0p, dW1p,
        dW01p, dW2p, dW02p, dVp, dV0p, outp, N);
}

// Round 9
// 401.008 us; speedup vs baseline: 1.2556x; 1.0061x over previous
//
#include <hip/hip_runtime.h>
#include <hip/hip_bf16.h>
#include <hip/hip_fp16.h>
#include <math.h>

#define MAXDEG 512

typedef short v8s __attribute__((ext_vector_type(8)));
typedef float v4f __attribute__((ext_vector_type(4)));
typedef _Float16 h2 __attribute__((ext_vector_type(2)));

// ---------------- block reduce helpers ----------------
__device__ __forceinline__ float blockReduceSum(float v) {
    __shared__ float sh[8];
    int lane = threadIdx.x & 63, w = threadIdx.x >> 6;
    for (int o = 32; o > 0; o >>= 1) v += __shfl_down(v, o);
    __syncthreads();
    if (lane == 0) sh[w] = v;
    __syncthreads();
    if (w == 0) {
        int nw = (blockDim.x + 63) >> 6;
        v = (lane < nw) ? sh[lane] : 0.f;
        for (int o = 4; o > 0; o >>= 1) v += __shfl_down(v, o);
        if (lane == 0) sh[0] = v;
    }
    __syncthreads();
    return sh[0];
}

__device__ __forceinline__ float blockReduceMax(float v) {
    __shared__ float sh[8];
    int lane = threadIdx.x & 63, w = threadIdx.x >> 6;
    for (int o = 32; o > 0; o >>= 1) v = fmaxf(v, __shfl_down(v, o));
    __syncthreads();
    if (lane == 0) sh[w] = v;
    __syncthreads();
    if (w == 0) {
        int nw = (blockDim.x + 63) >> 6;
        v = (lane < nw) ? sh[lane] : -3.4e38f;
        for (int o = 4; o > 0; o >>= 1) v = fmaxf(v, __shfl_down(v, o));
        if (lane == 0) sh[0] = v;
    }
    __syncthreads();
    return sh[0];
}

__device__ __forceinline__ float leaky(float x) { return x >= 0.f ? x : 0.2f * x; }

// ---------------- kernels ----------------

// Fused: blocks [0,4096) do CSR build + s_mat row sums; remaining blocks do
// hin conversion, weight transposes (fp16), and el/er zeroing.
__global__ void fused_pre(const float* __restrict__ adj, const float* __restrict__ s,
                          int* __restrict__ colIdx, int* __restrict__ deg,
                          float* __restrict__ dv,
                          const float* __restrict__ x, const int* __restrict__ obs,
                          const float* __restrict__ theta,
                          const float* __restrict__ Wh0, const float* __restrict__ Wh1,
                          const float* __restrict__ Wo0,
                          __half* __restrict__ hin, __half* __restrict__ Wh0t,
                          __half* __restrict__ Wh1t, __half* __restrict__ Wo0t,
                          float* __restrict__ elerZ, int elerN, int N) {
    if (blockIdx.x < 4096) {
        int row = blockIdx.x;
        __shared__ int cnt;
        if (threadIdx.x == 0) cnt = 0;
        __syncthreads();
        const float4* ar = (const float4*)(adj + (size_t)row * N);
        const float4* sr = (const float4*)(s + (size_t)row * N);
        int* outp = colIdx + (size_t)row * MAXDEG;
        float psum = 0.f;
        const int n4 = N >> 2;
        for (int j4 = threadIdx.x; j4 < n4; j4 += blockDim.x) {
            float4 a4 = ar[j4];
            float4 s4 = sr[j4];
            psum += (s4.x + s4.y) + (s4.z + s4.w);
            int jb = j4 << 2;
            if (a4.x > 0.f) { int p = atomicAdd(&cnt, 1); if (p < MAXDEG) outp[p] = jb; }
            if (a4.y > 0.f) { int p = atomicAdd(&cnt, 1); if (p < MAXDEG) outp[p] = jb + 1; }
            if (a4.z > 0.f) { int p = atomicAdd(&cnt, 1); if (p < MAXDEG) outp[p] = jb + 2; }
            if (a4.w > 0.f) { int p = atomicAdd(&cnt, 1); if (p < MAXDEG) outp[p] = jb + 3; }
        }
        psum = blockReduceSum(psum);
        __syncthreads();
        if (threadIdx.x == 0) {
            deg[row] = cnt < MAXDEG ? cnt : MAXDEG;
            dv[row] = psum;
        }
        return;
    }
    const int n0 = 4096 * 512;       // hin
    const int n1 = 4 * 512 * 256;    // Wh0t
    const int n2 = 4 * 256 * 256;    // Wh1t
    const int n3 = 1024 * 64;        // Wo0t
    int i = (blockIdx.x - 4096) * 256 + threadIdx.x;
    if (i < n0) {
        int n = i >> 9, f = i & 511;
        float v = x[i];
        if (obs[n] == 1) v += theta[f];
        hin[i] = __float2half(v);
    } else if (i < n0 + n1) {
        int t = i - n0;                         // [b][m<256][k<512]
        int b = t / (512 * 256), r = t % (512 * 256);
        int mm = r >> 9, kk = r & 511;
        Wh0t[t] = __float2half(Wh0[b * 512 * 256 + kk * 256 + mm]);
    } else if (i < n0 + n1 + n2) {
        int t = i - n0 - n1;                    // [b][m<256][k<256]
        int b = t >> 16, r = t & 65535;
        int mm = r >> 8, kk = r & 255;
        Wh1t[t] = __float2half(Wh1[b * 65536 + kk * 256 + mm]);
    } else if (i < n0 + n1 + n2 + n3) {
        int t = i - n0 - n1 - n2;               // [m<64][k<1024]
        int mm = t >> 10, kk = t & 1023;
        Wo0t[t] = __float2half(Wo0[kk * 64 + mm]);
    } else if (i < n0 + n1 + n2 + n3 + elerN) {
        elerZ[i - n0 - n1 - n2 - n3] = 0.f;
    }
}

// 128x128 block-tile MFMA GEMM (fp16 in/out): C[b] = A[b] @ Bt[b]^T with
// fused el/er epilogue (atomicAdd partials).
__global__ __launch_bounds__(256) void gemm_mfma128(
    const __half* __restrict__ A, const __half* __restrict__ Bt,
    __half* __restrict__ C, int N, int K, int M,
    size_t sA, size_t sB, size_t sC,
    const float* __restrict__ aVec, size_t aStride,
    float* __restrict__ el, float* __restrict__ er) {
    int b = blockIdx.z;
    const unsigned short* Ag = (const unsigned short*)(A + (size_t)b * sA);
    const unsigned short* Bg = (const unsigned short*)(Bt + (size_t)b * sB);
    __half* Cg = C + (size_t)b * sC;
    const float* av = aVec + (size_t)b * aStride;

    __shared__ __align__(16) unsigned short As[128][40];
    __shared__ __align__(16) unsigned short Bs[128][40];

    const int tid = threadIdx.x;
    const int wave = tid >> 6, lane = tid & 63;
    const int wm = wave >> 1, wn = wave & 1;
    const int row0 = blockIdx.y * 128, col0 = blockIdx.x * 128;
    const int lr = tid >> 2;
    const int lo = (tid & 3) * 8;
    const int m = lane & 15, quad = lane >> 4;

    v4f acc[4][4];
    #pragma unroll
    for (int i = 0; i < 4; i++)
        #pragma unroll
        for (int c = 0; c < 4; c++) acc[i][c] = (v4f)(0.f);

    for (int k0 = 0; k0 < K; k0 += 32) {
        *(int4*)(&As[lr][lo]) =
            *(const int4*)(Ag + (size_t)(row0 + lr) * K + k0 + lo);
        *(int4*)(&As[lr + 64][lo]) =
            *(const int4*)(Ag + (size_t)(row0 + 64 + lr) * K + k0 + lo);
        *(int4*)(&Bs[lr][lo]) =
            *(const int4*)(Bg + (size_t)(col0 + lr) * K + k0 + lo);
        *(int4*)(&Bs[lr + 64][lo]) =
            *(const int4*)(Bg + (size_t)(col0 + 64 + lr) * K + k0 + lo);
        __syncthreads();
        v8s af[4], bfv[4];
        #pragma unroll
        for (int i = 0; i < 4; i++)
            af[i] = *(const v8s*)(&As[wm * 64 + i * 16 + m][quad * 8]);
        #pragma unroll
        for (int c = 0; c < 4; c++)
            bfv[c] = *(const v8s*)(&Bs[wn * 64 + c * 16 + m][quad * 8]);
        #pragma unroll
        for (int i = 0; i < 4; i++)
            #pragma unroll
            for (int c = 0; c < 4; c++)
                acc[i][c] = __builtin_amdgcn_mfma_f32_16x16x32_f16(
                    af[i], bfv[c], acc[i][c], 0, 0, 0);
        __syncthreads();
    }
    #pragma unroll
    for (int i = 0; i < 4; i++)
        #pragma unroll
        for (int c = 0; c < 4; c++)
            #pragma unroll
            for (int r = 0; r < 4; r++) {
                int row = row0 + wm * 64 + i * 16 + quad * 4 + r;
                int col = col0 + wn * 64 + c * 16 + m;
                Cg[(size_t)row * M + col] = __float2half(acc[i][c][r]);
            }
    float ael[4], aer[4];
    #pragma unroll
    for (int c = 0; c < 4; c++) {
        ael[c] = av[col0 + wn * 64 + c * 16 + m];
        aer[c] = av[M + col0 + wn * 64 + c * 16 + m];
    }
    #pragma unroll
    for (int i = 0; i < 4; i++)
        #pragma unroll
        for (int r = 0; r < 4; r++) {
            float pel = 0.f, per_ = 0.f;
            #pragma unroll
            for (int c = 0; c < 4; c++) {
                pel += acc[i][c][r] * ael[c];
                per_ += acc[i][c][r] * aer[c];
            }
            #pragma unroll
            for (int off = 1; off < 16; off <<= 1) {
                pel += __shfl_xor(pel, off);
                per_ += __shfl_xor(per_, off);
            }
            if (m == 0) {
                int row = row0 + wm * 64 + i * 16 + quad * 4 + r;
                atomicAdd(&el[(size_t)b * N + row], pel);
                atomicAdd(&er[(size_t)b * N + row], per_);
            }
        }
}

// 64x64 tile GEMM (M=64 output layer), fp16 in/out, fused el/er.
__global__ __launch_bounds__(256) void gemm_mfma64(
    const __half* __restrict__ A, const __half* __restrict__ Bt,
    __half* __restrict__ C, int N, int K, int M,
    size_t sA, size_t sB, size_t sC,
    const float* __restrict__ aVec, size_t aStride,
    float* __restrict__ el, float* __restrict__ er) {
    int b = blockIdx.z;
    const unsigned short* Ag = (const unsigned short*)(A + (size_t)b * sA);
    const unsigned short* Bg = (const unsigned short*)(Bt + (size_t)b * sB);
    __half* Cg = C + (size_t)b * sC;
    const float* av = aVec + (size_t)b * aStride;

    __shared__ __align__(16) unsigned short As[64][40];
    __shared__ __align__(16) unsigned short Bs[64][40];

    const int tid = threadIdx.x;
    const int wave = tid >> 6, lane = tid & 63;
    const int row0 = blockIdx.y * 64, col0 = blockIdx.x * 64;
    const int sRow = tid >> 2;
    const int sOff = (tid & 3) * 8;
    const int m = lane & 15, quad = lane >> 4;

    v4f acc[4];
    #pragma unroll
    for (int c = 0; c < 4; c++) acc[c] = (v4f)(0.f);

    for (int k0 = 0; k0 < K; k0 += 32) {
        *(int4*)(&As[sRow][sOff]) =
            *(const int4*)(Ag + (size_t)(row0 + sRow) * K + k0 + sOff);
        *(int4*)(&Bs[sRow][sOff]) =
            *(const int4*)(Bg + (size_t)(col0 + sRow) * K + k0 + sOff);
        __syncthreads();
        v8s af = *(const v8s*)(&As[wave * 16 + m][quad * 8]);
        #pragma unroll
        for (int c = 0; c < 4; c++) {
            v8s bfv = *(const v8s*)(&Bs[c * 16 + m][quad * 8]);
            acc[c] = __builtin_amdgcn_mfma_f32_16x16x32_f16(af, bfv, acc[c], 0, 0, 0);
        }
        __syncthreads();
    }
    #pragma unroll
    for (int c = 0; c < 4; c++)
        #pragma unroll
        for (int r = 0; r < 4; r++) {
            int row = row0 + wave * 16 + quad * 4 + r;
            int col = col0 + c * 16 + m;
            Cg[(size_t)row * M + col] = __float2half(acc[c][r]);
        }
    float ael[4], aer[4];
    #pragma unroll
    for (int c = 0; c < 4; c++) {
        ael[c] = av[col0 + c * 16 + m];
        aer[c] = av[M + col0 + c * 16 + m];
    }
    #pragma unroll
    for (int r = 0; r < 4; r++) {
        float pel = 0.f, per_ = 0.f;
        #pragma unroll
        for (int c = 0; c < 4; c++) {
            pel += acc[c][r] * ael[c];
            per_ += acc[c][r] * aer[c];
        }
        #pragma unroll
        for (int off = 1; off < 16; off <<= 1) {
            pel += __shfl_xor(pel, off);
            per_ += __shfl_xor(per_, off);
        }
        if (m == 0) {
            int row = row0 + wave * 16 + quad * 4 + r;
            atomicAdd(&el[(size_t)b * N + row], pel);
            atomicAdd(&er[(size_t)b * N + row], per_);
        }
    }
}

// Masked softmax + fp16 gather, pair-structured for MLP: each sub handles 4
// adjacent neighbors per iter (2 pairs); one ds_read_b128 covers a pair's spc
// entries; 4 outstanding uint4 global loads per lane.
// FUSE=1 (D=64 only): instead of writing the row, dot with Wo1 -> o2wh/el4/er4.
template<int D, int ACT, int HEADS, int FUSE>
__global__ __launch_bounds__(256) void attn_vec(
    const __half* __restrict__ Wh, const float* __restrict__ el,
    const float* __restrict__ er, const int* __restrict__ colIdx,
    const int* __restrict__ deg, __half* __restrict__ out,
    int N, size_t sWh, size_t sOut, int outRowStride,
    const float* __restrict__ wo1, const float* __restrict__ ao1,
    float* __restrict__ o2wh, float* __restrict__ el4, float* __restrict__ er4) {
    constexpr int LPN = D / 8;          // lanes per neighbor (8 fp16/lane)
    constexpr int SUBS = 64 / LPN;      // sub-groups per wave
    constexpr int PER_WAVE = SUBS * 4;  // neighbors per wave per iteration
    constexpr int PAD = 4 * PER_WAVE;   // neighbors per block per iteration

    int b, row;
    if (HEADS == 4) {
        int blk = blockIdx.x;
        b = (blk & 7) >> 1;
        row = ((blk >> 3) << 1) | (blk & 1);
    } else {
        b = 0;
        row = blockIdx.x;
    }
    const int tid = threadIdx.x;
    const __half* whb = Wh + (size_t)b * sWh;
    const float* erb = er + (size_t)b * N;
    const float eln = el[(size_t)b * N + row];
    const int dc = deg[row];
    const int dcp = (dc + PAD - 1) & ~(PAD - 1);
    const int* ci = colIdx + (size_t)row * MAXDEG;

    __shared__ __align__(16) float2 spc[MAXDEG];  // {packed half2 p, byte off}
    __shared__ __align__(16) float redc[4 * D];

    float mx = -3.4e38f;
    for (int k = tid; k < dc; k += 256) {
        int j = ci[k];
        float s = eln + erb[j];
        s = fmaxf(s, 0.2f * s);               // LeakyReLU(0.2)
        spc[k] = make_float2(s, __int_as_float(j * (D * 2)));
        mx = fmaxf(mx, s);
    }
    for (int k = dc + tid; k < dcp; k += 256)
        spc[k] = make_float2(__int_as_float(0), __int_as_float(0));
    mx = blockReduceMax(mx);
    float l = 0.f;
    for (int k = tid; k < dc; k += 256) {
        float p = __expf(spc[k].x - mx);
        l += p;
        unsigned int pu = __half_as_ushort(__float2half(p));
        spc[k].x = __int_as_float(pu | (pu << 16));   // packed half2 {p,p}
    }
    l = blockReduceSum(l);
    const float inv = 1.f / l;

    const int wave = tid >> 6, lane = tid & 63;
    const int sub = lane / LPN;
    const int dl = (lane % LPN) * 8;
    const char* wp = (const char*)(whb + dl);

    union HU { unsigned int u; h2 h; };
    union R4 { uint4 u; h2 h[4]; };

    h2 a0[4], a1[4];
    #pragma unroll
    for (int i = 0; i < 4; i++) { a0[i] = (h2)(_Float16)0; a1[i] = (h2)(_Float16)0; }

    for (int k = wave * PER_WAVE + sub * 4; k < dcp; k += PAD) {
        float4 pA = *(const float4*)(&spc[k]);        // pair (k, k+1)
        float4 pB = *(const float4*)(&spc[k + 2]);    // pair (k+2, k+3)
        R4 r0, r1, r2, r3;
        r0.u = *(const uint4*)(wp + __float_as_int(pA.y));
        r1.u = *(const uint4*)(wp + __float_as_int(pA.w));
        r2.u = *(const uint4*)(wp + __float_as_int(pB.y));
        r3.u = *(const uint4*)(wp + __float_as_int(pB.w));
        HU p0, p1, p2, p3;
        p0.u = __float_as_int(pA.x);
        p1.u = __float_as_int(pA.z);
        p2.u = __float_as_int(pB.x);
        p3.u = __float_as_int(pB.z);
        #pragma unroll
        for (int i = 0; i < 4; i++) {
            a0[i] += p0.h * r0.h[i];
            a1[i] += p2.h * r2.h[i];
        }
        #pragma unroll
        for (int i = 0; i < 4; i++) {
            a0[i] += p1.h * r1.h[i];
            a1[i] += p3.h * r3.h[i];
        }
    }
    #pragma unroll
    for (int i = 0; i < 4; i++) a0[i] += a1[i];
    // cross-sub-group reduce on packed halves
    #pragma unroll
    for (int off = LPN; off < 64; off <<= 1)
        #pragma unroll
        for (int i = 0; i < 4; i++) {
            HU t, s;
            t.h = a0[i];
            s.u = __shfl_xor((int)t.u, off);
            a0[i] += s.h;
        }
    __syncthreads();
    if (sub == 0)
        #pragma unroll
        for (int i = 0; i < 4; i++) {
            redc[wave * D + dl + 2 * i]     = (float)a0[i][0];
            redc[wave * D + dl + 2 * i + 1] = (float)a0[i][1];
        }
    __syncthreads();
    if (FUSE) {
        if (tid < 64) {
            float vv = (redc[tid] + redc[D + tid] + redc[2 * D + tid] + redc[3 * D + tid]) * inv;
            float t = vv * wo1[tid];
            #pragma unroll
            for (int o = 32; o > 0; o >>= 1) t += __shfl_down(t, o);
            if (tid == 0) {
                o2wh[row] = t;
                el4[row] = t * ao1[0];
                er4[row] = t * ao1[1];
            }
        }
        return;
    }
    if (tid < D) {
        float v = (redc[tid] + redc[D + tid] + redc[2 * D + tid] + redc[3 * D + tid]) * inv;
        if (ACT == 1) v = (v > 0.f) ? v : expm1f(v);   // ELU
        out[(size_t)b * sOut + (size_t)row * outRowStride + tid] = __float2half(v);
    }
}

// D==1 attention + elu + degreeNN fused (one block per row).
__global__ void attn_d1_deg(const float* __restrict__ o2wh, const float* __restrict__ el,
                            const float* __restrict__ er, const int* __restrict__ colIdx,
                            const int* __restrict__ deg, const float* __restrict__ dv,
                            const float* __restrict__ dW, const float* __restrict__ dW0,
                            const float* __restrict__ dW1, const float* __restrict__ dW01,
                            const float* __restrict__ dW2, const float* __restrict__ dW02,
                            const float* __restrict__ dV, const float* __restrict__ dV0,
                            float* __restrict__ out, int N) {
    int row = blockIdx.x, tid = threadIdx.x;
    const float eln = el[row];
    const int dc = deg[row];
    const int* ci = colIdx + (size_t)row * MAXDEG;
    __shared__ float sp[MAXDEG];
    __shared__ int sc[MAXDEG];
    float mx = -3.4e38f;
    for (int k = tid; k < dc; k += blockDim.x) {
        int j = ci[k];
        sc[k] = j;
        float s = eln + er[j];
        s = fmaxf(s, 0.2f * s);
        sp[k] = s;
        mx = fmaxf(mx, s);
    }
    mx = blockReduceMax(mx);
    float l = 0.f, acc = 0.f;
    for (int k = tid; k < dc; k += blockDim.x) {
        float p = __expf(sp[k] - mx);
        l += p;
        acc += p * o2wh[sc[k]];
    }
    l = blockReduceSum(l);
    acc = blockReduceSum(acc);
    if (tid == 0) {
        float h = acc / l;
        h = (h > 0.f) ? h : expm1f(h);            // elu
        float d = dv[row];
        float t0[10], t1[20], t2[10];
        #pragma unroll
        for (int i = 0; i < 10; i++)
            t0[i] = leaky(h * dW[i] + d * dW[10 + i] + dW0[i]);
        #pragma unroll
        for (int j = 0; j < 20; j++) {
            float s = dW01[j];
            #pragma unroll
            for (int i = 0; i < 10; i++) s += t0[i] * dW1[i * 20 + j];
            t1[j] = leaky(s);
        }
        #pragma unroll
        for (int j = 0; j < 10; j++) {
            float s = dW02[j];
            #pragma unroll
            for (int i = 0; i < 20; i++) s += t1[i] * dW2[i * 10 + j];
            t2[j] = leaky(s);
        }
        float o = dV0[0];
        #pragma unroll
        for (int i = 0; i < 10; i++) o += t2[i] * dV[i];
        out[row] = leaky(o);
    }
}

// ---------------- launch ----------------
extern "C" void kernel_launch(void* const* d_in, const int* in_sizes, int n_in,
                              void* d_out, int out_size, void* d_ws, size_t ws_size,
                              hipStream_t stream) {
    const int N = 4096, F = 512, H = 4, D1 = 256, O1 = 64;
    const float* x     = (const float*)d_in[0];
    const float* adj   = (const float*)d_in[1];
    const int*   obs   = (const int*)  d_in[2];
    const float* s_mat = (const float*)d_in[3];
    const float* theta = (const float*)d_in[4];
    const float* Wh0   = (const float*)d_in[5];
    const float* ah0   = (const float*)d_in[6];
    const float* Wh1   = (const float*)d_in[7];
    const float* ah1   = (const float*)d_in[8];
    const float* Wo0   = (const float*)d_in[9];
    const float* ao0   = (const float*)d_in[10];
    const float* Wo1   = (const float*)d_in[11];
    const float* ao1   = (const float*)d_in[12];
    const float* dWp   = (const float*)d_in[13];
    const float* dW0p  = (const float*)d_in[14];
    const float* dW1p  = (const float*)d_in[15];
    const float* dW01p = (const float*)d_in[16];
    const float* dW2p  = (const float*)d_in[17];
    const float* dW02p = (const float*)d_in[18];
    const float* dVp   = (const float*)d_in[19];
    const float* dV0p  = (const float*)d_in[20];
    float* outp = (float*)d_out;

    char* ws = (char*)d_ws;
    auto alloc = [&](size_t bytes) {
        char* p = ws;
        ws += (bytes + 255) & ~(size_t)255;
        return p;
    };
    __half* hin  = (__half*)alloc((size_t)N * F * 2);
    __half* whA  = (__half*)alloc((size_t)H * N * D1 * 2);
    __half* hb   = (__half*)alloc((size_t)H * N * D1 * 2);
    __half* hcat = (__half*)alloc((size_t)N * H * D1 * 2);
    __half* o1Wh = (__half*)alloc((size_t)N * O1 * 2);
    float* o2Wh  = (float*)alloc((size_t)N * 4);
    __half* Wh0t = (__half*)alloc((size_t)H * F * D1 * 2);
    __half* Wh1t = (__half*)alloc((size_t)H * D1 * D1 * 2);
    __half* Wo0t = (__half*)alloc((size_t)H * D1 * O1 * 2);
    int elerN = 4 * H * N + 2 * N;
    float* elerZ = (float*)alloc((size_t)elerN * 4);
    float* el1 = elerZ;
    float* er1 = el1 + H * N;
    float* el2 = er1 + H * N;
    float* er2 = el2 + H * N;
    float* el3 = er2 + H * N;
    float* er3 = el3 + N;
    float* el4 = (float*)alloc((size_t)N * 4);
    float* er4 = (float*)alloc((size_t)N * 4);
    float* dv  = (float*)alloc((size_t)N * 4);
    int* colIdx = (int*)alloc((size_t)N * MAXDEG * 4);
    int* deg    = (int*)alloc((size_t)N * 4);

    {
        const int totalPrep = N * F + H * F * D1 + H * D1 * D1 + H * D1 * O1 + elerN;
        const int prepBlocks = (totalPrep + 255) / 256;
        fused_pre<<<4096 + prepBlocks, 256, 0, stream>>>(
            adj, s_mat, colIdx, deg, dv,
            x, obs, theta, Wh0, Wh1, Wo0, hin, Wh0t, Wh1t, Wo0t, elerZ, elerN, N);
    }

    // ----- multi-head layer 1 (D=256, elu) -----
    gemm_mfma128<<<dim3(D1 / 128, N / 128, H), 256, 0, stream>>>(
        hin, Wh0t, whA, N, F, D1, 0, (size_t)D1 * F, (size_t)N * D1,
        ah0, (size_t)2 * D1, el1, er1);
    attn_vec<256, 1, 4, 0><<<N * H, 256, 0, stream>>>(
        whA, el1, er1, colIdx, deg, hb,
        N, (size_t)N * D1, (size_t)N * D1, D1,
        nullptr, nullptr, nullptr, nullptr, nullptr);

    // ----- multi-head layer 2 (D=256, elu) -> hcat interleaved -----
    gemm_mfma128<<<dim3(D1 / 128, N / 128, H), 256, 0, stream>>>(
        hb, Wh1t, whA, N, D1, D1, (size_t)N * D1, (size_t)D1 * D1, (size_t)N * D1,
        ah1, (size_t)2 * D1, el2, er2);
    attn_vec<256, 1, 4, 0><<<N * H, 256, 0, stream>>>(
        whA, el2, er2, colIdx, deg, hcat,
        N, (size_t)N * D1, (size_t)D1, H * D1,
        nullptr, nullptr, nullptr, nullptr, nullptr);

    // ----- output layer 1 (D=64, no act) + fused matvec (Wo1) -----
    gemm_mfma64<<<dim3(O1 / 64, N / 64, 1), 256, 0, stream>>>(
        hcat, Wo0t, o1Wh, N, H * D1, O1, 0, 0, 0,
        ao0, 0, el3, er3);
    attn_vec<64, 0, 1, 1><<<N, 256, 0, stream>>>(
        o1Wh, el3, er3, colIdx, deg, nullptr,
        N, 0, 0, O1,
        Wo1, ao1, o2Wh, el4, er4);

    // ----- output layer 2 (D=1) + elu + degreeNN -----
    attn_d1_deg<<<N, 256, 0, stream>>>(o2Wh, el4, er4, colIdx, deg, dv,
        dWp, dW0p, dW1p, dW01p, dW2p, dW02p, dVp, dV0p, outp, N);
}